// Round 1
// baseline (2821.238 us; speedup 1.0000x reference)
//
#include <hip/hip_runtime.h>

#define BB 8
#define TT 1024
#define DD 512
#define HH 8
#define HS 64

// ---------------- LayerNorm: one block per row ----------------
__global__ __launch_bounds__(256) void ln_kernel(const float* __restrict__ in,
                                                 const float* __restrict__ gamma,
                                                 const float* __restrict__ beta,
                                                 float* __restrict__ x) {
  int row = blockIdx.x;
  const float* r = in + (size_t)row * DD;
  int t = threadIdx.x;
  float a = r[t];
  float b = r[t + 256];
  float s = a + b;
#pragma unroll
  for (int o = 32; o > 0; o >>= 1) s += __shfl_down(s, o);
  __shared__ float red[8];
  if ((t & 63) == 0) red[t >> 6] = s;
  __syncthreads();
  float mean = (red[0] + red[1] + red[2] + red[3]) * (1.0f / DD);
  float da = a - mean, db = b - mean;
  float vs = da * da + db * db;
#pragma unroll
  for (int o = 32; o > 0; o >>= 1) vs += __shfl_down(vs, o);
  __syncthreads();
  if ((t & 63) == 0) red[t >> 6] = vs;
  __syncthreads();
  float var = (red[0] + red[1] + red[2] + red[3]) * (1.0f / DD);
  float inv = rsqrtf(var + 1e-3f);
  float* xr = x + (size_t)row * DD;
  xr[t]       = da * inv * gamma[t] + beta[t];
  xr[t + 256] = db * inv * gamma[t + 256] + beta[t + 256];
}

// ------------- per-head projection GEMM: Out[row, h*64+o] = sum_i X[row,i]*W[h,i,o] -------------
// X: [8192,512] row-major. W: [H][512][64]. Out: [8192][512].
__global__ __launch_bounds__(256) void proj_gemm(const float* __restrict__ X,
                                                 const float* __restrict__ W,
                                                 float* __restrict__ Out) {
  int rb = blockIdx.x;  // 128 row-blocks of 64
  int h  = blockIdx.y;  // 8 heads
  __shared__ float As[16][64];
  __shared__ float Bs[16][64];
  int tid = threadIdx.x;
  int tm = (tid >> 4) << 2;
  int tn = (tid & 15) << 2;
  float acc[4][4] = {};
  const float* Wh = W + (size_t)h * DD * HS;
  int am = tid >> 2, ak = (tid & 3) << 2;
  int bk = tid >> 4, bn = (tid & 15) << 2;
  for (int k0 = 0; k0 < DD; k0 += 16) {
    float4 av = *(const float4*)(X + (size_t)(rb * 64 + am) * DD + k0 + ak);
    As[ak + 0][am] = av.x; As[ak + 1][am] = av.y; As[ak + 2][am] = av.z; As[ak + 3][am] = av.w;
    *(float4*)&Bs[bk][bn] = *(const float4*)(Wh + (size_t)(k0 + bk) * HS + bn);
    __syncthreads();
#pragma unroll
    for (int kq = 0; kq < 16; ++kq) {
      float4 a = *(const float4*)&As[kq][tm];
      float4 b = *(const float4*)&Bs[kq][tn];
      acc[0][0] += a.x * b.x; acc[0][1] += a.x * b.y; acc[0][2] += a.x * b.z; acc[0][3] += a.x * b.w;
      acc[1][0] += a.y * b.x; acc[1][1] += a.y * b.y; acc[1][2] += a.y * b.z; acc[1][3] += a.y * b.w;
      acc[2][0] += a.z * b.x; acc[2][1] += a.z * b.y; acc[2][2] += a.z * b.z; acc[2][3] += a.z * b.w;
      acc[3][0] += a.w * b.x; acc[3][1] += a.w * b.y; acc[3][2] += a.w * b.z; acc[3][3] += a.w * b.w;
    }
    __syncthreads();
  }
#pragma unroll
  for (int i = 0; i < 4; ++i) {
    float4 v = make_float4(acc[i][0], acc[i][1], acc[i][2], acc[i][3]);
    *(float4*)(Out + (size_t)(rb * 64 + tm + i) * DD + h * HS + tn) = v;
  }
}

// ------------- output projection + bias + residual -------------
// A: pre [8192][512] (col = h*64+o). P: [512][512] (row k=h*64+o, col i). Out[row,i] = resid + bias + A@P
__global__ __launch_bounds__(256) void out_gemm(const float* __restrict__ A,
                                                const float* __restrict__ P,
                                                const float* __restrict__ resid,
                                                const float* __restrict__ bias,
                                                float* __restrict__ Out) {
  int rb = blockIdx.x;
  int cb = blockIdx.y;  // 8 col-blocks of 64
  __shared__ float As[16][64];
  __shared__ float Bs[16][64];
  int tid = threadIdx.x;
  int tm = (tid >> 4) << 2;
  int tn = (tid & 15) << 2;
  float acc[4][4] = {};
  int am = tid >> 2, ak = (tid & 3) << 2;
  int bk = tid >> 4, bn = (tid & 15) << 2;
  for (int k0 = 0; k0 < DD; k0 += 16) {
    float4 av = *(const float4*)(A + (size_t)(rb * 64 + am) * DD + k0 + ak);
    As[ak + 0][am] = av.x; As[ak + 1][am] = av.y; As[ak + 2][am] = av.z; As[ak + 3][am] = av.w;
    *(float4*)&Bs[bk][bn] = *(const float4*)(P + (size_t)(k0 + bk) * DD + cb * 64 + bn);
    __syncthreads();
#pragma unroll
    for (int kq = 0; kq < 16; ++kq) {
      float4 a = *(const float4*)&As[kq][tm];
      float4 b = *(const float4*)&Bs[kq][tn];
      acc[0][0] += a.x * b.x; acc[0][1] += a.x * b.y; acc[0][2] += a.x * b.z; acc[0][3] += a.x * b.w;
      acc[1][0] += a.y * b.x; acc[1][1] += a.y * b.y; acc[1][2] += a.y * b.z; acc[1][3] += a.y * b.w;
      acc[2][0] += a.z * b.x; acc[2][1] += a.z * b.y; acc[2][2] += a.z * b.z; acc[2][3] += a.z * b.w;
      acc[3][0] += a.w * b.x; acc[3][1] += a.w * b.y; acc[3][2] += a.w * b.z; acc[3][3] += a.w * b.w;
    }
    __syncthreads();
  }
#pragma unroll
  for (int i = 0; i < 4; ++i) {
    size_t base = (size_t)(rb * 64 + tm + i) * DD + cb * 64 + tn;
    float4 rs = *(const float4*)(resid + base);
    float4 bi = *(const float4*)(bias + cb * 64 + tn);
    float4 v = make_float4(acc[i][0] + rs.x + bi.x, acc[i][1] + rs.y + bi.y,
                           acc[i][2] + rs.z + bi.z, acc[i][3] + rs.w + bi.w);
    *(float4*)(Out + base) = v;
  }
}

// ------------- fused rel-shift attention: scores + softmax + AV per (b,h,8-row block) -------------
// q,k,v,p: [B,T,H,HS]; u,vb: [H,HS]; pre: [B,T,H,HS]
#define RB 8
__global__ __launch_bounds__(256) void attn_kernel(const float* __restrict__ q,
                                                   const float* __restrict__ k,
                                                   const float* __restrict__ v,
                                                   const float* __restrict__ p,
                                                   const float* __restrict__ u,
                                                   const float* __restrict__ vbias,
                                                   float* __restrict__ pre) {
  int nb = blockIdx.x;  // 128 row-blocks
  int h  = blockIdx.y;
  int b  = blockIdx.z;
  int n0 = nb * RB;
  int tid = threadIdx.x;
  __shared__ float qu[RB][HS];
  __shared__ float qv[RB + 1][HS];
  __shared__ float sc[RB][TT];

  for (int i = tid; i < RB * HS; i += 256) {
    int r = i >> 6, o = i & 63;
    float qval = q[(((size_t)b * TT + (n0 + r)) * HH + h) * HS + o];
    qu[r][o] = qval + u[h * HS + o];
    qv[r][o] = qval + vbias[h * HS + o];
  }
  for (int i = tid; i < HS; i += 256) {
    int row = min(n0 + RB, TT - 1);  // clamped; unused when OOB
    qv[RB][i] = q[(((size_t)b * TT + row) * HH + h) * HS + i] + vbias[h * HS + i];
  }
  __syncthreads();

  // phase 2a: content scores  sc[r][m] = qu[r] . k[m]
  const float* kb = k + (((size_t)b * TT) * HH + h) * HS;
  for (int ci = 0; ci < 4; ++ci) {
    int m = ci * 256 + tid;
    float4 kr[16];
#pragma unroll
    for (int j = 0; j < 16; ++j) kr[j] = *(const float4*)(kb + (size_t)m * HH * HS + j * 4);
#pragma unroll
    for (int r = 0; r < RB; ++r) {
      float acc = 0.f;
#pragma unroll
      for (int j = 0; j < 16; ++j) {
        float4 a = *(const float4*)&qu[r][j * 4];
        acc += a.x * kr[j].x + a.y * kr[j].y + a.z * kr[j].z + a.w * kr[j].w;
      }
      sc[r][m] = acc;
    }
  }
  __syncthreads();

  // phase 2b: position scores, unshifted bd[n0+r][c] scattered into shifted slots.
  // shifted[n][m] = bd[n][1023-(n-m)] (m<=n) ; 0 (m==n+1) ; bd[n+1][m-n-2] (m>=n+2)
  const float* pb = p + (((size_t)b * TT) * HH + h) * HS;
  for (int ci = 0; ci < 4; ++ci) {
    int c = ci * 256 + tid;
    float4 pr[16];
#pragma unroll
    for (int j = 0; j < 16; ++j) pr[j] = *(const float4*)(pb + (size_t)c * HH * HS + j * 4);
#pragma unroll
    for (int r = 0; r <= RB; ++r) {
      float acc = 0.f;
#pragma unroll
      for (int j = 0; j < 16; ++j) {
        float4 a = *(const float4*)&qv[r][j * 4];
        acc += a.x * pr[j].x + a.y * pr[j].y + a.z * pr[j].z + a.w * pr[j].w;
      }
      int n = n0 + r;
      int m1 = c + n - (TT - 1);              // lands in row r (m<=n)
      if (r < RB && m1 >= 0) sc[r][m1] += acc;
      int m2 = c + n + 1;                     // lands in row r-1 (m>=n+2)
      if (r >= 1 && m2 <= TT - 1) sc[r - 1][m2] += acc;
    }
  }
  __syncthreads();

  // phase 3: softmax per row (wave w handles rows 2w, 2w+1), scale 1/sqrt(64)
  int lane = tid & 63, wv = tid >> 6;
  for (int rr = 0; rr < 2; ++rr) {
    int r = wv * 2 + rr;
    float vals[16];
    float mx = -1e30f;
#pragma unroll
    for (int j = 0; j < 16; ++j) {
      vals[j] = sc[r][lane + 64 * j] * 0.125f;
      mx = fmaxf(mx, vals[j]);
    }
#pragma unroll
    for (int o = 32; o > 0; o >>= 1) mx = fmaxf(mx, __shfl_xor(mx, o));
    float sum = 0.f;
#pragma unroll
    for (int j = 0; j < 16; ++j) { vals[j] = __expf(vals[j] - mx); sum += vals[j]; }
#pragma unroll
    for (int o = 32; o > 0; o >>= 1) sum += __shfl_xor(sum, o);
    float inv = 1.0f / sum;
#pragma unroll
    for (int j = 0; j < 16; ++j) sc[r][lane + 64 * j] = vals[j] * inv;
  }
  __syncthreads();

  // phase 4: AV. thread -> (o, row-group); rows rg and rg+4
  const float* vbase = v + (((size_t)b * TT) * HH + h) * HS;
  int o = tid & 63, rg = tid >> 6;
  float acc0 = 0.f, acc1 = 0.f;
  for (int m = 0; m < TT; ++m) {
    float vvv = vbase[(size_t)m * HH * HS + o];
    acc0 += sc[rg][m] * vvv;
    acc1 += sc[rg + 4][m] * vvv;
  }
  pre[(((size_t)b * TT + (n0 + rg)) * HH + h) * HS + o] = acc0;
  pre[(((size_t)b * TT + (n0 + rg + 4)) * HH + h) * HS + o] = acc1;
}

extern "C" void kernel_launch(void* const* d_in, const int* in_sizes, int n_in,
                              void* d_out, int out_size, void* d_ws, size_t ws_size,
                              hipStream_t stream) {
  const float* inputs = (const float*)d_in[0];
  const float* pos    = (const float*)d_in[1];
  const float* gamma  = (const float*)d_in[2];
  const float* beta   = (const float*)d_in[3];
  const float* Wq = (const float*)d_in[4];
  const float* Wk = (const float*)d_in[5];
  const float* Wv = (const float*)d_in[6];
  const float* Wp = (const float*)d_in[7];
  const float* bu = (const float*)d_in[8];
  const float* bv = (const float*)d_in[9];
  const float* Wo = (const float*)d_in[10];
  const float* bo = (const float*)d_in[11];
  float* out = (float*)d_out;
  float* ws  = (float*)d_ws;

  const size_t NROW = (size_t)BB * TT;  // 8192
  float* x   = ws;
  float* q   = x + NROW * DD;
  float* kk  = q + NROW * DD;
  float* vv  = kk + NROW * DD;
  float* pp  = vv + NROW * DD;
  float* pre = pp + NROW * DD;  // total 24M floats = 96 MB

  ln_kernel<<<dim3(NROW), dim3(256), 0, stream>>>(inputs, gamma, beta, x);
  proj_gemm<<<dim3(128, 8), dim3(256), 0, stream>>>(x, Wq, q);
  proj_gemm<<<dim3(128, 8), dim3(256), 0, stream>>>(x, Wk, kk);
  proj_gemm<<<dim3(128, 8), dim3(256), 0, stream>>>(x, Wv, vv);
  proj_gemm<<<dim3(128, 8), dim3(256), 0, stream>>>(pos, Wp, pp);
  attn_kernel<<<dim3(TT / RB, HH, BB), dim3(256), 0, stream>>>(q, kk, vv, pp, bu, bv, pre);
  out_gemm<<<dim3(128, 8), dim3(256), 0, stream>>>(pre, Wo, inputs, bo, out);
}

// Round 3
// 521.240 us; speedup vs baseline: 5.4126x; 5.4126x over previous
//
#include <hip/hip_runtime.h>

#define BB 8
#define TT 1024
#define DD 512
#define HH 8
#define HS 64

typedef __attribute__((ext_vector_type(8))) short short8;
typedef __attribute__((ext_vector_type(4))) float f32x4;

__device__ __forceinline__ float bf2f(unsigned short u) {
  union { unsigned int i; float f; } v; v.i = ((unsigned int)u) << 16; return v.f;
}
__device__ __forceinline__ unsigned short f2bf(float f) {
  union { float f; unsigned int i; } v; v.f = f;
  unsigned int i = v.i;
  return (unsigned short)((i + 0x7FFFu + ((i >> 16) & 1u)) >> 16);
}

// ---------------- LayerNorm: one block per row ----------------
__global__ __launch_bounds__(256) void ln_kernel(const float* __restrict__ in,
                                                 const float* __restrict__ gamma,
                                                 const float* __restrict__ beta,
                                                 float* __restrict__ x) {
  int row = blockIdx.x;
  const float* r = in + (size_t)row * DD;
  int t = threadIdx.x;
  float a = r[t];
  float b = r[t + 256];
  float s = a + b;
#pragma unroll
  for (int o = 32; o > 0; o >>= 1) s += __shfl_down(s, o);
  __shared__ float red[8];
  if ((t & 63) == 0) red[t >> 6] = s;
  __syncthreads();
  float mean = (red[0] + red[1] + red[2] + red[3]) * (1.0f / DD);
  float da = a - mean, db = b - mean;
  float vs = da * da + db * db;
#pragma unroll
  for (int o = 32; o > 0; o >>= 1) vs += __shfl_down(vs, o);
  __syncthreads();
  if ((t & 63) == 0) red[t >> 6] = vs;
  __syncthreads();
  float var = (red[0] + red[1] + red[2] + red[3]) * (1.0f / DD);
  float inv = rsqrtf(var + 1e-3f);
  float* xr = x + (size_t)row * DD;
  xr[t]       = da * inv * gamma[t] + beta[t];
  xr[t + 256] = db * inv * gamma[t + 256] + beta[t + 256];
}

// ---------- GEMM core macro: computes acc[4][4] for 64x64 tile (rb,h) ----------
#define PROJ_CORE(XPTR, WPTR)                                                        \
  int rb = blockIdx.x, h = blockIdx.y;                                               \
  __shared__ float As[16][64];                                                       \
  __shared__ float Bs[16][64];                                                       \
  int tid = threadIdx.x;                                                             \
  int tm = (tid >> 4) << 2, tn = (tid & 15) << 2;                                    \
  float acc[4][4] = {};                                                              \
  const float* Wh = (WPTR) + (size_t)h * DD * HS;                                    \
  int am = tid >> 2, ak = (tid & 3) << 2;                                            \
  int bk = tid >> 4, bn = (tid & 15) << 2;                                           \
  for (int k0 = 0; k0 < DD; k0 += 16) {                                              \
    float4 av = *(const float4*)((XPTR) + (size_t)(rb * 64 + am) * DD + k0 + ak);    \
    As[ak + 0][am] = av.x; As[ak + 1][am] = av.y;                                    \
    As[ak + 2][am] = av.z; As[ak + 3][am] = av.w;                                    \
    *(float4*)&Bs[bk][bn] = *(const float4*)(Wh + (size_t)(k0 + bk) * HS + bn);      \
    __syncthreads();                                                                 \
    _Pragma("unroll")                                                                \
    for (int kq = 0; kq < 16; ++kq) {                                                \
      float4 a = *(const float4*)&As[kq][tm];                                        \
      float4 b = *(const float4*)&Bs[kq][tn];                                        \
      acc[0][0] += a.x * b.x; acc[0][1] += a.x * b.y; acc[0][2] += a.x * b.z; acc[0][3] += a.x * b.w; \
      acc[1][0] += a.y * b.x; acc[1][1] += a.y * b.y; acc[1][2] += a.y * b.z; acc[1][3] += a.y * b.w; \
      acc[2][0] += a.z * b.x; acc[2][1] += a.z * b.y; acc[2][2] += a.z * b.z; acc[2][3] += a.z * b.w; \
      acc[3][0] += a.w * b.x; acc[3][1] += a.w * b.y; acc[3][2] += a.w * b.z; acc[3][3] += a.w * b.w; \
    }                                                                                \
    __syncthreads();                                                                 \
  }

// Q projection -> QU = 0.125*(q + bias_u), QV = 0.125*(q + bias_v), bf16 [B][H][T][HS]
__global__ __launch_bounds__(256) void proj_q(const float* __restrict__ X,
                                              const float* __restrict__ W,
                                              const float* __restrict__ bu,
                                              const float* __restrict__ bv,
                                              unsigned short* __restrict__ QU,
                                              unsigned short* __restrict__ QV) {
  PROJ_CORE(X, W)
  const float S = 0.125f;
  float4 buv = *(const float4*)(bu + h * HS + tn);
  float4 bvv = *(const float4*)(bv + h * HS + tn);
#pragma unroll
  for (int i = 0; i < 4; ++i) {
    int rr = rb * 64 + tm + i;
    int bb = rr >> 10, n = rr & 1023;
    size_t base = (((size_t)bb * HH + h) * TT + n) * HS + tn;
    ushort4 uq, vq;
    uq.x = f2bf((acc[i][0] + buv.x) * S); uq.y = f2bf((acc[i][1] + buv.y) * S);
    uq.z = f2bf((acc[i][2] + buv.z) * S); uq.w = f2bf((acc[i][3] + buv.w) * S);
    vq.x = f2bf((acc[i][0] + bvv.x) * S); vq.y = f2bf((acc[i][1] + bvv.y) * S);
    vq.z = f2bf((acc[i][2] + bvv.z) * S); vq.w = f2bf((acc[i][3] + bvv.w) * S);
    *(ushort4*)(QU + base) = uq;
    *(ushort4*)(QV + base) = vq;
  }
}

// K / P projection -> bf16 [B][H][T][HS]
__global__ __launch_bounds__(256) void proj_kp(const float* __restrict__ X,
                                               const float* __restrict__ W,
                                               unsigned short* __restrict__ Out) {
  PROJ_CORE(X, W)
#pragma unroll
  for (int i = 0; i < 4; ++i) {
    int rr = rb * 64 + tm + i;
    int bb = rr >> 10, n = rr & 1023;
    size_t base = (((size_t)bb * HH + h) * TT + n) * HS + tn;
    ushort4 q;
    q.x = f2bf(acc[i][0]); q.y = f2bf(acc[i][1]);
    q.z = f2bf(acc[i][2]); q.w = f2bf(acc[i][3]);
    *(ushort4*)(Out + base) = q;
  }
}

// V projection -> TRANSPOSED bf16 [B][H][HS][T]
__global__ __launch_bounds__(256) void proj_v(const float* __restrict__ X,
                                              const float* __restrict__ W,
                                              unsigned short* __restrict__ Vt) {
  PROJ_CORE(X, W)
  __shared__ float T[64][65];
#pragma unroll
  for (int i = 0; i < 4; ++i)
#pragma unroll
    for (int j = 0; j < 4; ++j) T[tm + i][tn + j] = acc[i][j];
  __syncthreads();
  int o = tid >> 2, g = tid & 3;
  int b = rb >> 4;
  size_t base = (((size_t)b * HH + h) * HS + o) * TT + (rb & 15) * 64 + g * 16;
  short8 pk, pk2;
#pragma unroll
  for (int i = 0; i < 8; ++i) pk[i] = (short)f2bf(T[g * 16 + i][o]);
#pragma unroll
  for (int i = 0; i < 8; ++i) pk2[i] = (short)f2bf(T[g * 16 + 8 + i][o]);
  *(short8*)(Vt + base) = pk;
  *(short8*)(Vt + base + 8) = pk2;
}

// ------------- output projection + bias + residual (f32) -------------
__global__ __launch_bounds__(256) void out_gemm(const float* __restrict__ A,
                                                const float* __restrict__ P,
                                                const float* __restrict__ resid,
                                                const float* __restrict__ bias,
                                                float* __restrict__ Out) {
  int rb = blockIdx.x;
  int cb = blockIdx.y;
  __shared__ float As[16][64];
  __shared__ float Bs[16][64];
  int tid = threadIdx.x;
  int tm = (tid >> 4) << 2;
  int tn = (tid & 15) << 2;
  float acc[4][4] = {};
  int am = tid >> 2, ak = (tid & 3) << 2;
  int bk = tid >> 4, bn = (tid & 15) << 2;
  for (int k0 = 0; k0 < DD; k0 += 16) {
    float4 av = *(const float4*)(A + (size_t)(rb * 64 + am) * DD + k0 + ak);
    As[ak + 0][am] = av.x; As[ak + 1][am] = av.y; As[ak + 2][am] = av.z; As[ak + 3][am] = av.w;
    *(float4*)&Bs[bk][bn] = *(const float4*)(P + (size_t)(k0 + bk) * DD + cb * 64 + bn);
    __syncthreads();
#pragma unroll
    for (int kq = 0; kq < 16; ++kq) {
      float4 a = *(const float4*)&As[kq][tm];
      float4 b = *(const float4*)&Bs[kq][tn];
      acc[0][0] += a.x * b.x; acc[0][1] += a.x * b.y; acc[0][2] += a.x * b.z; acc[0][3] += a.x * b.w;
      acc[1][0] += a.y * b.x; acc[1][1] += a.y * b.y; acc[1][2] += a.y * b.z; acc[1][3] += a.y * b.w;
      acc[2][0] += a.z * b.x; acc[2][1] += a.z * b.y; acc[2][2] += a.z * b.z; acc[2][3] += a.z * b.w;
      acc[3][0] += a.w * b.x; acc[3][1] += a.w * b.y; acc[3][2] += a.w * b.z; acc[3][3] += a.w * b.w;
    }
    __syncthreads();
  }
#pragma unroll
  for (int i = 0; i < 4; ++i) {
    size_t base = (size_t)(rb * 64 + tm + i) * DD + cb * 64 + tn;
    float4 rs = *(const float4*)(resid + base);
    float4 bi = *(const float4*)(bias + cb * 64 + tn);
    float4 v = make_float4(acc[i][0] + rs.x + bi.x, acc[i][1] + rs.y + bi.y,
                           acc[i][2] + rs.z + bi.z, acc[i][3] + rs.w + bi.w);
    *(float4*)(Out + base) = v;
  }
}

// ------------- fused MFMA rel-attention: per (b,h,64-row block), 8 waves -------------
// QU,QV,K,P: bf16 [B][H][T][64]; Vt: bf16 [B][H][64][T]; pre: f32 [B][T][H][64]
__global__ __launch_bounds__(512) void attn_mfma(const unsigned short* __restrict__ QU,
                                                 const unsigned short* __restrict__ QV,
                                                 const unsigned short* __restrict__ Kg,
                                                 const unsigned short* __restrict__ Vt,
                                                 const unsigned short* __restrict__ Pg,
                                                 float* __restrict__ pre) {
  int nb = blockIdx.x, h = blockIdx.y, b = blockIdx.z;
  int n0 = nb * 64;
  __shared__ __align__(16) unsigned short Wl[65][1032];   // unshifted BD rows n0..n0+64
  __shared__ __align__(16) unsigned short Pl[8][16][40];  // per-wave P staging (80B rows)
  int tid = threadIdx.x;
  int w = tid >> 6, l = tid & 63;
  int l15 = l & 15, l4 = l >> 4;
  size_t bh = (size_t)b * HH + h;
  const unsigned short* QUb = QU + bh * (TT * HS);
  const unsigned short* QVb = QV + bh * (TT * HS);
  const unsigned short* Kb  = Kg + bh * (TT * HS);
  const unsigned short* Pb  = Pg + bh * (TT * HS);
  const unsigned short* Vb  = Vt + bh * (HS * TT);

  // ---- prepass: W[0..63][c] = QV[n0+r] . P[c] via MFMA ----
  {
    int rg = w >> 1, ch = w & 1;
    const unsigned short* arow = QVb + (size_t)(n0 + 16 * rg + l15) * HS;
    short8 a0 = *(const short8*)(arow + l4 * 8);
    short8 a1 = *(const short8*)(arow + 32 + l4 * 8);
    for (int cg = 0; cg < 32; ++cg) {
      int c0 = ch * 512 + cg * 16;
      const unsigned short* brow = Pb + (size_t)(c0 + l15) * HS;
      short8 b0 = *(const short8*)(brow + l4 * 8);
      short8 b1 = *(const short8*)(brow + 32 + l4 * 8);
      f32x4 acc = {0.f, 0.f, 0.f, 0.f};
      acc = __builtin_amdgcn_mfma_f32_16x16x32_bf16(a0, b0, acc, 0, 0, 0);
      acc = __builtin_amdgcn_mfma_f32_16x16x32_bf16(a1, b1, acc, 0, 0, 0);
      int r = 16 * rg + l4 * 4;
      int c = c0 + l15;
#pragma unroll
      for (int j = 0; j < 4; ++j) Wl[r + j][c] = f2bf(acc[j]);
    }
  }
  // ---- W row 64 via VALU dots (only read when n0 <= 958) ----
  {
    int qr = n0 + 64; if (qr > TT - 1) qr = TT - 1;
    const unsigned short* q64 = QVb + (size_t)qr * HS;
    for (int c = tid; c < TT; c += 512) {
      const unsigned short* prow = Pb + (size_t)c * HS;
      float s = 0.f;
#pragma unroll
      for (int k = 0; k < HS; ++k) s += bf2f(q64[k]) * bf2f(prow[k]);
      Wl[64][c] = f2bf(s);
    }
  }
  __syncthreads();

  // ---- main loop: wave (wr,wc) owns rows [16wr,16wr+16), cols {m: (m&63) in [32wc,32wc+32)} ----
  int wr = w >> 1, wc = w & 1;
  const unsigned short* qrow = QUb + (size_t)(n0 + 16 * wr + l15) * HS;
  short8 qa0 = *(const short8*)(qrow + l4 * 8);
  short8 qa1 = *(const short8*)(qrow + 32 + l4 * 8);
  float run_m[4], run_l[4];
  f32x4 Oa[4];
#pragma unroll
  for (int j = 0; j < 4; ++j) {
    run_m[j] = -1e30f; run_l[j] = 0.f;
    Oa[j].x = 0.f; Oa[j].y = 0.f; Oa[j].z = 0.f; Oa[j].w = 0.f;
  }
  unsigned short* myP = &Pl[w][0][0];
  int r0 = 16 * wr + l4 * 4;

  for (int ms = 0; ms < 16; ++ms) {
    int mb0 = ms * 64 + 32 * wc;
    // AC scores: two 16-col fragments
    f32x4 s0 = {0.f, 0.f, 0.f, 0.f}, s1 = {0.f, 0.f, 0.f, 0.f};
    {
      const unsigned short* k0p = Kb + (size_t)(mb0 + l15) * HS;
      short8 kb0 = *(const short8*)(k0p + l4 * 8);
      short8 kb1 = *(const short8*)(k0p + 32 + l4 * 8);
      s0 = __builtin_amdgcn_mfma_f32_16x16x32_bf16(qa0, kb0, s0, 0, 0, 0);
      s0 = __builtin_amdgcn_mfma_f32_16x16x32_bf16(qa1, kb1, s0, 0, 0, 0);
      const unsigned short* k1p = Kb + (size_t)(mb0 + 16 + l15) * HS;
      short8 kc0 = *(const short8*)(k1p + l4 * 8);
      short8 kc1 = *(const short8*)(k1p + 32 + l4 * 8);
      s1 = __builtin_amdgcn_mfma_f32_16x16x32_bf16(qa0, kc0, s1, 0, 0, 0);
      s1 = __builtin_amdgcn_mfma_f32_16x16x32_bf16(qa1, kc1, s1, 0, 0, 0);
    }
    // BD gather-add from Wl (rel-shift as index math)
#pragma unroll
    for (int f = 0; f < 2; ++f) {
      int m = mb0 + 16 * f + l15;
#pragma unroll
      for (int j = 0; j < 4; ++j) {
        int r = r0 + j;
        int n = n0 + r;
        bool below = (m <= n);
        int row = below ? r : (r + 1);
        int cc = below ? (1023 - n + m) : (m - n - 2);
        cc = cc < 0 ? 0 : cc;
        float bd = bf2f(Wl[row][cc]);
        bd = (m == n + 1) ? 0.f : bd;
        if (f == 0) s0[j] += bd; else s1[j] += bd;
      }
    }
    // online softmax (per row j, reduce across the 16 lanes of each l>>4 group)
    float nm[4], fac[4];
#pragma unroll
    for (int j = 0; j < 4; ++j) {
      float t = fmaxf(s0[j], s1[j]);
      t = fmaxf(t, __shfl_xor(t, 1));
      t = fmaxf(t, __shfl_xor(t, 2));
      t = fmaxf(t, __shfl_xor(t, 4));
      t = fmaxf(t, __shfl_xor(t, 8));
      float m2 = fmaxf(run_m[j], t);
      fac[j] = __expf(run_m[j] - m2);
      nm[j] = m2;
    }
#pragma unroll
    for (int j = 0; j < 4; ++j) {
      s0[j] = __expf(s0[j] - nm[j]);
      s1[j] = __expf(s1[j] - nm[j]);
      float ps = s0[j] + s1[j];
      ps += __shfl_xor(ps, 1);
      ps += __shfl_xor(ps, 2);
      ps += __shfl_xor(ps, 4);
      ps += __shfl_xor(ps, 8);
      run_l[j] = run_l[j] * fac[j] + ps;
      run_m[j] = nm[j];
    }
#pragma unroll
    for (int of = 0; of < 4; ++of) {
#pragma unroll
      for (int j = 0; j < 4; ++j) Oa[of][j] *= fac[j];
    }
    // P -> LDS (C-layout) -> A-frag layout read-back
#pragma unroll
    for (int j = 0; j < 4; ++j) {
      myP[(l4 * 4 + j) * 40 + l15]      = f2bf(s0[j]);
      myP[(l4 * 4 + j) * 40 + 16 + l15] = f2bf(s1[j]);
    }
    short8 pa = *(const short8*)(myP + l15 * 40 + l4 * 8);
    // PV: O[r][o] += P[r][k] * Vt[o][mb0+k]
#pragma unroll
    for (int of = 0; of < 4; ++of) {
      const unsigned short* vrow = Vb + (size_t)(of * 16 + l15) * TT + mb0 + l4 * 8;
      short8 vb = *(const short8*)(vrow);
      Oa[of] = __builtin_amdgcn_mfma_f32_16x16x32_bf16(pa, vb, Oa[of], 0, 0, 0);
    }
  }

  // ---- merge wc halves (split-KV combine), write pre ----
  __syncthreads();
  float* Xch = (float*)&Wl[0][0];
  if (wc == 1) {
#pragma unroll
    for (int of = 0; of < 4; ++of)
#pragma unroll
      for (int j = 0; j < 4; ++j)
        Xch[(wr * 16 + l4 * 4 + j) * 64 + of * 16 + l15] = Oa[of][j];
    if (l15 == 0) {
#pragma unroll
      for (int j = 0; j < 4; ++j) {
        Xch[4096 + (wr * 16 + l4 * 4 + j) * 2 + 0] = run_m[j];
        Xch[4096 + (wr * 16 + l4 * 4 + j) * 2 + 1] = run_l[j];
      }
    }
  }
  __syncthreads();
  if (wc == 0) {
#pragma unroll
    for (int j = 0; j < 4; ++j) {
      int row = wr * 16 + l4 * 4 + j;
      float m1 = Xch[4096 + row * 2 + 0];
      float l1 = Xch[4096 + row * 2 + 1];
      float M = fmaxf(run_m[j], m1);
      float a0 = __expf(run_m[j] - M);
      float a1 = __expf(m1 - M);
      float inv = 1.0f / (run_l[j] * a0 + l1 * a1);
      float sa0 = a0 * inv, sa1 = a1 * inv;
#pragma unroll
      for (int of = 0; of < 4; ++of) {
        float o1 = Xch[row * 64 + of * 16 + l15];
        pre[(((size_t)b * TT + (n0 + row)) * HH + h) * HS + of * 16 + l15] =
            Oa[of][j] * sa0 + o1 * sa1;
      }
    }
  }
}

extern "C" void kernel_launch(void* const* d_in, const int* in_sizes, int n_in,
                              void* d_out, int out_size, void* d_ws, size_t ws_size,
                              hipStream_t stream) {
  const float* inputs = (const float*)d_in[0];
  const float* pos    = (const float*)d_in[1];
  const float* gamma  = (const float*)d_in[2];
  const float* beta   = (const float*)d_in[3];
  const float* Wq = (const float*)d_in[4];
  const float* Wk = (const float*)d_in[5];
  const float* Wv = (const float*)d_in[6];
  const float* Wp = (const float*)d_in[7];
  const float* bu = (const float*)d_in[8];
  const float* bv = (const float*)d_in[9];
  const float* Wo = (const float*)d_in[10];
  const float* bo = (const float*)d_in[11];
  float* out = (float*)d_out;
  char* w8 = (char*)d_ws;

  const size_t NROW = (size_t)BB * TT;                 // 8192
  const size_t TSZ  = NROW * DD;                       // elements per full tensor (4.19M)
  float* x   = (float*)w8;                             // 16 MB
  float* pre = (float*)(w8 + 16777216);                // 16 MB
  unsigned short* QUp = (unsigned short*)(w8 + 33554432);   // 8 MB each (B*H*T*HS bf16)
  unsigned short* QVp = QUp + TSZ;
  unsigned short* Kp  = QVp + TSZ;
  unsigned short* Vtp = Kp  + TSZ;
  unsigned short* Pp  = Vtp + TSZ;                     // total 72 MB

  ln_kernel<<<dim3(NROW), dim3(256), 0, stream>>>(inputs, gamma, beta, x);
  proj_q <<<dim3(128, 8), dim3(256), 0, stream>>>(x, Wq, bu, bv, QUp, QVp);
  proj_kp<<<dim3(128, 8), dim3(256), 0, stream>>>(x, Wk, Kp);
  proj_v <<<dim3(128, 8), dim3(256), 0, stream>>>(x, Wv, Vtp);
  proj_kp<<<dim3(128, 8), dim3(256), 0, stream>>>(pos, Wp, Pp);
  attn_mfma<<<dim3(TT / 64, HH, BB), dim3(512), 0, stream>>>(QUp, QVp, Kp, Vtp, Pp, pre);
  out_gemm<<<dim3(128, 8), dim3(256), 0, stream>>>(pre, Wo, inputs, bo, out);
}

// Round 4
// 442.809 us; speedup vs baseline: 6.3712x; 1.1771x over previous
//
#include <hip/hip_runtime.h>

#define BB 8
#define TT 1024
#define DD 512
#define HH 8
#define HS 64

typedef __attribute__((ext_vector_type(8))) short short8;
typedef __attribute__((ext_vector_type(4))) float f32x4;

__device__ __forceinline__ float bf2f(unsigned short u) {
  union { unsigned int i; float f; } v; v.i = ((unsigned int)u) << 16; return v.f;
}
__device__ __forceinline__ unsigned short f2bf(float f) {
  union { float f; unsigned int i; } v; v.f = f;
  unsigned int i = v.i;
  return (unsigned short)((i + 0x7FFFu + ((i >> 16) & 1u)) >> 16);
}

// ---------------- LayerNorm: one block per row, bf16 output ----------------
__global__ __launch_bounds__(256) void ln_kernel(const float* __restrict__ in,
                                                 const float* __restrict__ gamma,
                                                 const float* __restrict__ beta,
                                                 unsigned short* __restrict__ x) {
  int row = blockIdx.x;
  const float* r = in + (size_t)row * DD;
  int t = threadIdx.x;
  float a = r[t];
  float b = r[t + 256];
  float s = a + b;
#pragma unroll
  for (int o = 32; o > 0; o >>= 1) s += __shfl_down(s, o);
  __shared__ float red[8];
  if ((t & 63) == 0) red[t >> 6] = s;
  __syncthreads();
  float mean = (red[0] + red[1] + red[2] + red[3]) * (1.0f / DD);
  float da = a - mean, db = b - mean;
  float vs = da * da + db * db;
#pragma unroll
  for (int o = 32; o > 0; o >>= 1) vs += __shfl_down(vs, o);
  __syncthreads();
  if ((t & 63) == 0) red[t >> 6] = vs;
  __syncthreads();
  float var = (red[0] + red[1] + red[2] + red[3]) * (1.0f / DD);
  float inv = rsqrtf(var + 1e-3f);
  unsigned short* xr = x + (size_t)row * DD;
  xr[t]       = f2bf(da * inv * gamma[t] + beta[t]);
  xr[t + 256] = f2bf(db * inv * gamma[t + 256] + beta[t + 256]);
}

// ---------------- weight transposes: [H][512][64] f32 -> [H][64][512] bf16 ----------------
__global__ __launch_bounds__(256) void transpose_qkvp(const float* __restrict__ Wq, const float* __restrict__ Wk,
                                                      const float* __restrict__ Wv, const float* __restrict__ Wp,
                                                      unsigned short* __restrict__ Tq, unsigned short* __restrict__ Tk,
                                                      unsigned short* __restrict__ Tv, unsigned short* __restrict__ Tp) {
  int h = blockIdx.x, sel = blockIdx.y;
  const float* in = sel == 0 ? Wq : sel == 1 ? Wk : sel == 2 ? Wv : Wp;
  unsigned short* out = sel == 0 ? Tq : sel == 1 ? Tk : sel == 2 ? Tv : Tp;
  __shared__ float Tl[64][65];
  int tid = threadIdx.x;
  int r = tid >> 2, qq = tid & 3;
  for (int t = 0; t < 8; ++t) {
    __syncthreads();
#pragma unroll
    for (int j = 0; j < 4; ++j)
      *(float4*)&Tl[r][qq * 16 + j * 4] =
          *(const float4*)(in + ((size_t)h * 512 + t * 64 + r) * 64 + qq * 16 + j * 4);
    __syncthreads();
#pragma unroll
    for (int j = 0; j < 4; ++j) {
      ushort4 u;
      u.x = f2bf(Tl[qq * 16 + j * 4 + 0][r]);
      u.y = f2bf(Tl[qq * 16 + j * 4 + 1][r]);
      u.z = f2bf(Tl[qq * 16 + j * 4 + 2][r]);
      u.w = f2bf(Tl[qq * 16 + j * 4 + 3][r]);
      *(ushort4*)(out + ((size_t)h * 64 + r) * 512 + t * 64 + qq * 16 + j * 4) = u;
    }
  }
}

// Wo: [512(k=h*64+o)][512(i)] f32 -> WoT [512(i)][512(k)] bf16
__global__ __launch_bounds__(256) void transpose_wo(const float* __restrict__ in,
                                                    unsigned short* __restrict__ out) {
  int tr = blockIdx.x, tc = blockIdx.y;
  __shared__ float Tl[64][65];
  int tid = threadIdx.x;
  int r = tid >> 2, qq = tid & 3;
#pragma unroll
  for (int j = 0; j < 4; ++j)
    *(float4*)&Tl[r][qq * 16 + j * 4] =
        *(const float4*)(in + ((size_t)tr * 64 + r) * 512 + tc * 64 + qq * 16 + j * 4);
  __syncthreads();
#pragma unroll
  for (int j = 0; j < 4; ++j) {
    ushort4 u;
    u.x = f2bf(Tl[qq * 16 + j * 4 + 0][r]);
    u.y = f2bf(Tl[qq * 16 + j * 4 + 1][r]);
    u.z = f2bf(Tl[qq * 16 + j * 4 + 2][r]);
    u.w = f2bf(Tl[qq * 16 + j * 4 + 3][r]);
    *(ushort4*)(out + ((size_t)tc * 64 + r) * 512 + tr * 64 + qq * 16 + j * 4) = u;
  }
}

// ---------------- MFMA projection kernels: 64x64 tile, K=512, 4 waves ----------------
#define PMF_PROLOG                                 \
  int tid = threadIdx.x;                           \
  int w = tid >> 6, l = tid & 63;                  \
  int l15 = l & 15, l4 = l >> 4;                   \
  int rb = blockIdx.x, h = blockIdx.y;             \
  int arow = rb * 64 + w * 16 + l15;               \
  f32x4 cf0 = {0.f,0.f,0.f,0.f}, cf1 = cf0, cf2 = cf0, cf3 = cf0;

#define PMF_KSTEP(AEXPR)                                                              \
  for (int k0 = 0; k0 < DD; k0 += 32) {                                               \
    short8 a = (AEXPR);                                                               \
    short8 b0 = *(const short8*)(Wth + (size_t)(0 * 16 + l15) * DD + k0 + l4 * 8);    \
    short8 b1 = *(const short8*)(Wth + (size_t)(1 * 16 + l15) * DD + k0 + l4 * 8);    \
    short8 b2 = *(const short8*)(Wth + (size_t)(2 * 16 + l15) * DD + k0 + l4 * 8);    \
    short8 b3 = *(const short8*)(Wth + (size_t)(3 * 16 + l15) * DD + k0 + l4 * 8);    \
    cf0 = __builtin_amdgcn_mfma_f32_16x16x32_bf16(a, b0, cf0, 0, 0, 0);               \
    cf1 = __builtin_amdgcn_mfma_f32_16x16x32_bf16(a, b1, cf1, 0, 0, 0);               \
    cf2 = __builtin_amdgcn_mfma_f32_16x16x32_bf16(a, b2, cf2, 0, 0, 0);               \
    cf3 = __builtin_amdgcn_mfma_f32_16x16x32_bf16(a, b3, cf3, 0, 0, 0);               \
  }

__device__ __forceinline__ short8 ldbf8(const unsigned short* p) { return *(const short8*)p; }

// Q projection -> QU/QV bf16 [B][H][T][HS], bias+scale folded
__global__ __launch_bounds__(256) void proj_mfma_q(const unsigned short* __restrict__ X,
                                                   const unsigned short* __restrict__ Wt,
                                                   const float* __restrict__ bu,
                                                   const float* __restrict__ bv,
                                                   unsigned short* __restrict__ QU,
                                                   unsigned short* __restrict__ QV) {
  PMF_PROLOG
  const unsigned short* Wth = Wt + (size_t)h * HS * DD;
  PMF_KSTEP(ldbf8(X + (size_t)arow * DD + k0 + l4 * 8))
  const float S = 0.125f;
  f32x4 cfs[4] = {cf0, cf1, cf2, cf3};
#pragma unroll
  for (int of = 0; of < 4; ++of) {
    int o = of * 16 + l15;
    float bum = bu[h * HS + o], bvm = bv[h * HS + o];
#pragma unroll
    for (int j = 0; j < 4; ++j) {
      int r = rb * 64 + w * 16 + l4 * 4 + j;
      int b = r >> 10, n = r & 1023;
      size_t base = (((size_t)b * HH + h) * TT + n) * HS + o;
      QU[base] = f2bf((cfs[of][j] + bum) * S);
      QV[base] = f2bf((cfs[of][j] + bvm) * S);
    }
  }
}

// K projection (bf16 in) -> bf16 [B][H][T][HS]
__global__ __launch_bounds__(256) void proj_mfma_k(const unsigned short* __restrict__ X,
                                                   const unsigned short* __restrict__ Wt,
                                                   unsigned short* __restrict__ Out) {
  PMF_PROLOG
  const unsigned short* Wth = Wt + (size_t)h * HS * DD;
  PMF_KSTEP(ldbf8(X + (size_t)arow * DD + k0 + l4 * 8))
  f32x4 cfs[4] = {cf0, cf1, cf2, cf3};
#pragma unroll
  for (int of = 0; of < 4; ++of) {
    int o = of * 16 + l15;
#pragma unroll
    for (int j = 0; j < 4; ++j) {
      int r = rb * 64 + w * 16 + l4 * 4 + j;
      int b = r >> 10, n = r & 1023;
      Out[(((size_t)b * HH + h) * TT + n) * HS + o] = f2bf(cfs[of][j]);
    }
  }
}

// P projection (f32 pos in) -> bf16 [B][H][T][HS]
__global__ __launch_bounds__(256) void proj_mfma_p(const float* __restrict__ Xf,
                                                   const unsigned short* __restrict__ Wt,
                                                   unsigned short* __restrict__ Out) {
  PMF_PROLOG
  const unsigned short* Wth = Wt + (size_t)h * HS * DD;
  for (int k0 = 0; k0 < DD; k0 += 32) {
    const float* ap = Xf + (size_t)arow * DD + k0 + l4 * 8;
    float4 av0 = *(const float4*)ap, av1 = *(const float4*)(ap + 4);
    short8 a;
    a[0] = (short)f2bf(av0.x); a[1] = (short)f2bf(av0.y); a[2] = (short)f2bf(av0.z); a[3] = (short)f2bf(av0.w);
    a[4] = (short)f2bf(av1.x); a[5] = (short)f2bf(av1.y); a[6] = (short)f2bf(av1.z); a[7] = (short)f2bf(av1.w);
    short8 b0 = *(const short8*)(Wth + (size_t)(0 * 16 + l15) * DD + k0 + l4 * 8);
    short8 b1 = *(const short8*)(Wth + (size_t)(1 * 16 + l15) * DD + k0 + l4 * 8);
    short8 b2 = *(const short8*)(Wth + (size_t)(2 * 16 + l15) * DD + k0 + l4 * 8);
    short8 b3 = *(const short8*)(Wth + (size_t)(3 * 16 + l15) * DD + k0 + l4 * 8);
    cf0 = __builtin_amdgcn_mfma_f32_16x16x32_bf16(a, b0, cf0, 0, 0, 0);
    cf1 = __builtin_amdgcn_mfma_f32_16x16x32_bf16(a, b1, cf1, 0, 0, 0);
    cf2 = __builtin_amdgcn_mfma_f32_16x16x32_bf16(a, b2, cf2, 0, 0, 0);
    cf3 = __builtin_amdgcn_mfma_f32_16x16x32_bf16(a, b3, cf3, 0, 0, 0);
  }
  f32x4 cfs[4] = {cf0, cf1, cf2, cf3};
#pragma unroll
  for (int of = 0; of < 4; ++of) {
    int o = of * 16 + l15;
#pragma unroll
    for (int j = 0; j < 4; ++j) {
      int r = rb * 64 + w * 16 + l4 * 4 + j;
      int b = r >> 10, n = r & 1023;
      Out[(((size_t)b * HH + h) * TT + n) * HS + o] = f2bf(cfs[of][j]);
    }
  }
}

// V projection -> TRANSPOSED bf16 [B][H][HS][T]
__global__ __launch_bounds__(256) void proj_mfma_v(const unsigned short* __restrict__ X,
                                                   const unsigned short* __restrict__ Wt,
                                                   unsigned short* __restrict__ Vt) {
  PMF_PROLOG
  const unsigned short* Wth = Wt + (size_t)h * HS * DD;
  PMF_KSTEP(ldbf8(X + (size_t)arow * DD + k0 + l4 * 8))
  __shared__ float Tl[64][65];
  f32x4 cfs[4] = {cf0, cf1, cf2, cf3};
#pragma unroll
  for (int of = 0; of < 4; ++of)
#pragma unroll
    for (int j = 0; j < 4; ++j)
      Tl[w * 16 + l4 * 4 + j][of * 16 + l15] = cfs[of][j];
  __syncthreads();
  int o = tid >> 2, qq = tid & 3;
  int b = rb >> 4;
  int n0 = (rb & 15) * 64;
  size_t base = (((size_t)b * HH + h) * HS + o) * TT + n0 + qq * 16;
  short8 p0, p1;
#pragma unroll
  for (int i = 0; i < 8; ++i) p0[i] = (short)f2bf(Tl[qq * 16 + i][o]);
#pragma unroll
  for (int i = 0; i < 8; ++i) p1[i] = (short)f2bf(Tl[qq * 16 + 8 + i][o]);
  *(short8*)(Vt + base) = p0;
  *(short8*)(Vt + base + 8) = p1;
}

// ---------------- output projection (MFMA) + bias + residual ----------------
__global__ __launch_bounds__(256) void out_mfma(const unsigned short* __restrict__ A,
                                                const unsigned short* __restrict__ WoT,
                                                const float* __restrict__ resid,
                                                const float* __restrict__ bias,
                                                float* __restrict__ Out) {
  int tid = threadIdx.x;
  int w = tid >> 6, l = tid & 63;
  int l15 = l & 15, l4 = l >> 4;
  int rb = blockIdx.x, cb = blockIdx.y;
  int arow = rb * 64 + w * 16 + l15;
  f32x4 cf0 = {0.f,0.f,0.f,0.f}, cf1 = cf0, cf2 = cf0, cf3 = cf0;
  const unsigned short* Wth = WoT + (size_t)cb * 64 * DD;
  PMF_KSTEP(ldbf8(A + (size_t)arow * DD + k0 + l4 * 8))
  f32x4 cfs[4] = {cf0, cf1, cf2, cf3};
#pragma unroll
  for (int of = 0; of < 4; ++of) {
    int i = cb * 64 + of * 16 + l15;
    float bi = bias[i];
#pragma unroll
    for (int j = 0; j < 4; ++j) {
      int r = rb * 64 + w * 16 + l4 * 4 + j;
      Out[(size_t)r * DD + i] = cfs[of][j] + bi + resid[(size_t)r * DD + i];
    }
  }
}

// ------------- fused MFMA rel-attention: QBLK=32, 8 waves (2 wr x 4 wc), XCD-swizzled -------------
// QU,QV,K,P: bf16 [B][H][T][64]; Vt: bf16 [B][H][64][T]; pre: bf16 [B][T][H*64]
__global__ __launch_bounds__(512, 4) void attn_mfma(const unsigned short* __restrict__ QU,
                                                    const unsigned short* __restrict__ QV,
                                                    const unsigned short* __restrict__ Kg,
                                                    const unsigned short* __restrict__ Vt,
                                                    const unsigned short* __restrict__ Pg,
                                                    unsigned short* __restrict__ pre) {
  // XCD-aware swizzle: all 32 nb-blocks of a (b,h) pair land on one XCD (idx%8 constant)
  int i = blockIdx.x;            // 0..2047
  int slot = i >> 3;             // 0..255
  int p = (i & 7) * 8 + (slot >> 5);  // pair 0..63
  int nb = slot & 31;
  int b = p >> 3, h = p & 7;
  int n0 = nb * 32;
  __shared__ __align__(16) unsigned short Wl[33][1032];   // unshifted BD rows n0..n0+32 (68.1 KB)
  __shared__ __align__(16) unsigned short Pl[8][16][40];  // per-wave P staging (10.2 KB)
  int tid = threadIdx.x;
  int w = tid >> 6, l = tid & 63;
  int l15 = l & 15, l4 = l >> 4;
  size_t bh = (size_t)b * HH + h;
  const unsigned short* QUb = QU + bh * (TT * HS);
  const unsigned short* QVb = QV + bh * (TT * HS);
  const unsigned short* Kb  = Kg + bh * (TT * HS);
  const unsigned short* Pb  = Pg + bh * (TT * HS);
  const unsigned short* Vb  = Vt + bh * (HS * TT);

  // ---- prepass: W[0..31][c] = QV[n0+r] . P[c] via MFMA; wave = (rg, ch) ----
  {
    int rg = w >> 2, ch = w & 3;
    const unsigned short* arow = QVb + (size_t)(n0 + 16 * rg + l15) * HS;
    short8 a0 = *(const short8*)(arow + l4 * 8);
    short8 a1 = *(const short8*)(arow + 32 + l4 * 8);
    for (int cg = 0; cg < 16; ++cg) {
      int c0 = ch * 256 + cg * 16;
      const unsigned short* brow = Pb + (size_t)(c0 + l15) * HS;
      short8 b0 = *(const short8*)(brow + l4 * 8);
      short8 b1 = *(const short8*)(brow + 32 + l4 * 8);
      f32x4 acc = {0.f, 0.f, 0.f, 0.f};
      acc = __builtin_amdgcn_mfma_f32_16x16x32_bf16(a0, b0, acc, 0, 0, 0);
      acc = __builtin_amdgcn_mfma_f32_16x16x32_bf16(a1, b1, acc, 0, 0, 0);
      int r = 16 * rg + l4 * 4;
      int c = c0 + l15;
#pragma unroll
      for (int j = 0; j < 4; ++j) Wl[r + j][c] = f2bf(acc[j]);
    }
  }
  // ---- W row 32 via VALU dots (needed for last row's upper-diag gather) ----
  {
    int qr = n0 + 32; if (qr > TT - 1) qr = TT - 1;
    const unsigned short* q32 = QVb + (size_t)qr * HS;
    for (int c = tid; c < TT; c += 512) {
      const unsigned short* prow = Pb + (size_t)c * HS;
      float s = 0.f;
#pragma unroll
      for (int k = 0; k < HS; ++k) s += bf2f(q32[k]) * bf2f(prow[k]);
      Wl[32][c] = f2bf(s);
    }
  }
  __syncthreads();

  // ---- main loop: wave (wr,wc): rows [16wr,16wr+16), cols mb0 = ms*128 + 32*wc ----
  int wr = w >> 2, wc = w & 3;
  const unsigned short* qrow = QUb + (size_t)(n0 + 16 * wr + l15) * HS;
  short8 qa0 = *(const short8*)(qrow + l4 * 8);
  short8 qa1 = *(const short8*)(qrow + 32 + l4 * 8);
  float run_m[4], run_l[4];
  f32x4 Oa[4];
#pragma unroll
  for (int j = 0; j < 4; ++j) {
    run_m[j] = -1e30f; run_l[j] = 0.f;
    Oa[j].x = 0.f; Oa[j].y = 0.f; Oa[j].z = 0.f; Oa[j].w = 0.f;
  }
  unsigned short* myP = &Pl[w][0][0];
  int r0 = 16 * wr + l4 * 4;

  for (int ms = 0; ms < 8; ++ms) {
    int mb0 = ms * 128 + 32 * wc;
    f32x4 s0 = {0.f, 0.f, 0.f, 0.f}, s1 = {0.f, 0.f, 0.f, 0.f};
    {
      const unsigned short* k0p = Kb + (size_t)(mb0 + l15) * HS;
      short8 kb0 = *(const short8*)(k0p + l4 * 8);
      short8 kb1 = *(const short8*)(k0p + 32 + l4 * 8);
      s0 = __builtin_amdgcn_mfma_f32_16x16x32_bf16(qa0, kb0, s0, 0, 0, 0);
      s0 = __builtin_amdgcn_mfma_f32_16x16x32_bf16(qa1, kb1, s0, 0, 0, 0);
      const unsigned short* k1p = Kb + (size_t)(mb0 + 16 + l15) * HS;
      short8 kc0 = *(const short8*)(k1p + l4 * 8);
      short8 kc1 = *(const short8*)(k1p + 32 + l4 * 8);
      s1 = __builtin_amdgcn_mfma_f32_16x16x32_bf16(qa0, kc0, s1, 0, 0, 0);
      s1 = __builtin_amdgcn_mfma_f32_16x16x32_bf16(qa1, kc1, s1, 0, 0, 0);
    }
    // BD gather-add from Wl (rel-shift as index math)
#pragma unroll
    for (int f = 0; f < 2; ++f) {
      int m = mb0 + 16 * f + l15;
#pragma unroll
      for (int j = 0; j < 4; ++j) {
        int r = r0 + j;
        int n = n0 + r;
        bool below = (m <= n);
        int row = below ? r : (r + 1);
        int cc = below ? (1023 - n + m) : (m - n - 2);
        cc = cc < 0 ? 0 : cc;
        float bd = bf2f(Wl[row][cc]);
        bd = (m == n + 1) ? 0.f : bd;
        if (f == 0) s0[j] += bd; else s1[j] += bd;
      }
    }
    // online softmax (reduce across 16-lane groups)
    float nm[4], fac[4];
#pragma unroll
    for (int j = 0; j < 4; ++j) {
      float t = fmaxf(s0[j], s1[j]);
      t = fmaxf(t, __shfl_xor(t, 1));
      t = fmaxf(t, __shfl_xor(t, 2));
      t = fmaxf(t, __shfl_xor(t, 4));
      t = fmaxf(t, __shfl_xor(t, 8));
      float m2 = fmaxf(run_m[j], t);
      fac[j] = __expf(run_m[j] - m2);
      nm[j] = m2;
    }
#pragma unroll
    for (int j = 0; j < 4; ++j) {
      s0[j] = __expf(s0[j] - nm[j]);
      s1[j] = __expf(s1[j] - nm[j]);
      float ps = s0[j] + s1[j];
      ps += __shfl_xor(ps, 1);
      ps += __shfl_xor(ps, 2);
      ps += __shfl_xor(ps, 4);
      ps += __shfl_xor(ps, 8);
      run_l[j] = run_l[j] * fac[j] + ps;
      run_m[j] = nm[j];
    }
#pragma unroll
    for (int of = 0; of < 4; ++of) {
#pragma unroll
      for (int j = 0; j < 4; ++j) Oa[of][j] *= fac[j];
    }
    // P -> LDS (C-layout) -> A-frag layout read-back
#pragma unroll
    for (int j = 0; j < 4; ++j) {
      myP[(l4 * 4 + j) * 40 + l15]      = f2bf(s0[j]);
      myP[(l4 * 4 + j) * 40 + 16 + l15] = f2bf(s1[j]);
    }
    short8 pa = *(const short8*)(myP + l15 * 40 + l4 * 8);
    // PV: O[r][o] += P[r][k] * Vt[o][mb0+k]
#pragma unroll
    for (int of = 0; of < 4; ++of) {
      const unsigned short* vrow = Vb + (size_t)(of * 16 + l15) * TT + mb0 + l4 * 8;
      short8 vb = *(const short8*)(vrow);
      Oa[of] = __builtin_amdgcn_mfma_f32_16x16x32_bf16(pa, vb, Oa[of], 0, 0, 0);
    }
  }

  // ---- 4-way split-KV merge across wc, write pre (bf16) ----
  __syncthreads();
  float* Xch = (float*)&Wl[0][0];
  if (wc != 0) {
    int base = w * 1088;
#pragma unroll
    for (int of = 0; of < 4; ++of)
#pragma unroll
      for (int j = 0; j < 4; ++j)
        Xch[base + (l4 * 4 + j) * 64 + of * 16 + l15] = Oa[of][j];
    if (l15 == 0) {
#pragma unroll
      for (int j = 0; j < 4; ++j) {
        Xch[base + 1024 + (l4 * 4 + j) * 2 + 0] = run_m[j];
        Xch[base + 1024 + (l4 * 4 + j) * 2 + 1] = run_l[j];
      }
    }
  }
  __syncthreads();
  if (wc == 0) {
#pragma unroll
    for (int j = 0; j < 4; ++j) {
      int row = l4 * 4 + j;
      float m0 = run_m[j], l0 = run_l[j];
      float m1 = Xch[(w + 1) * 1088 + 1024 + row * 2 + 0];
      float l1 = Xch[(w + 1) * 1088 + 1024 + row * 2 + 1];
      float m2 = Xch[(w + 2) * 1088 + 1024 + row * 2 + 0];
      float l2 = Xch[(w + 2) * 1088 + 1024 + row * 2 + 1];
      float m3 = Xch[(w + 3) * 1088 + 1024 + row * 2 + 0];
      float l3 = Xch[(w + 3) * 1088 + 1024 + row * 2 + 1];
      float M = fmaxf(fmaxf(m0, m1), fmaxf(m2, m3));
      float a0 = __expf(m0 - M), a1 = __expf(m1 - M), a2 = __expf(m2 - M), a3 = __expf(m3 - M);
      float inv = 1.0f / (l0 * a0 + l1 * a1 + l2 * a2 + l3 * a3);
#pragma unroll
      for (int of = 0; of < 4; ++of) {
        int o = of * 16 + l15;
        float v = Oa[of][j] * a0
                + Xch[(w + 1) * 1088 + row * 64 + o] * a1
                + Xch[(w + 2) * 1088 + row * 64 + o] * a2
                + Xch[(w + 3) * 1088 + row * 64 + o] * a3;
        int rg = 16 * wr + row;
        pre[((size_t)b * TT + n0 + rg) * DD + h * HS + o] = f2bf(v * inv);
      }
    }
  }
}

extern "C" void kernel_launch(void* const* d_in, const int* in_sizes, int n_in,
                              void* d_out, int out_size, void* d_ws, size_t ws_size,
                              hipStream_t stream) {
  const float* inputs = (const float*)d_in[0];
  const float* pos    = (const float*)d_in[1];
  const float* gamma  = (const float*)d_in[2];
  const float* beta   = (const float*)d_in[3];
  const float* Wq = (const float*)d_in[4];
  const float* Wk = (const float*)d_in[5];
  const float* Wv = (const float*)d_in[6];
  const float* Wp = (const float*)d_in[7];
  const float* bu = (const float*)d_in[8];
  const float* bv = (const float*)d_in[9];
  const float* Wo = (const float*)d_in[10];
  const float* bo = (const float*)d_in[11];
  float* out = (float*)d_out;
  unsigned short* w16 = (unsigned short*)d_ws;

  const size_t T2 = (size_t)BB * TT * DD;   // 4.19M elems per full tensor
  unsigned short* x_bf  = w16;              // 8 MB each
  unsigned short* pre_b = x_bf  + T2;
  unsigned short* QUp   = pre_b + T2;
  unsigned short* QVp   = QUp   + T2;
  unsigned short* Kp    = QVp   + T2;
  unsigned short* Vtp   = Kp    + T2;
  unsigned short* Pp    = Vtp   + T2;
  unsigned short* WtQ   = Pp    + T2;       // 512 KB each
  unsigned short* WtK   = WtQ + 262144;
  unsigned short* WtV   = WtK + 262144;
  unsigned short* WtP   = WtV + 262144;
  unsigned short* WoT   = WtP + 262144;

  transpose_qkvp<<<dim3(8, 4), dim3(256), 0, stream>>>(Wq, Wk, Wv, Wp, WtQ, WtK, WtV, WtP);
  transpose_wo<<<dim3(8, 8), dim3(256), 0, stream>>>(Wo, WoT);
  ln_kernel<<<dim3(BB * TT), dim3(256), 0, stream>>>(inputs, gamma, beta, x_bf);
  proj_mfma_q<<<dim3(128, 8), dim3(256), 0, stream>>>(x_bf, WtQ, bu, bv, QUp, QVp);
  proj_mfma_k<<<dim3(128, 8), dim3(256), 0, stream>>>(x_bf, WtK, Kp);
  proj_mfma_v<<<dim3(128, 8), dim3(256), 0, stream>>>(x_bf, WtV, Vtp);
  proj_mfma_p<<<dim3(128, 8), dim3(256), 0, stream>>>(pos, WtP, Pp);
  attn_mfma<<<dim3(2048), dim3(512), 0, stream>>>(QUp, QVp, Kp, Vtp, Pp, pre_b);
  out_mfma<<<dim3(128, 8), dim3(256), 0, stream>>>(pre_b, WoT, inputs, bo, out);
}

// Round 5
// 394.828 us; speedup vs baseline: 7.1455x; 1.1215x over previous
//
#include <hip/hip_runtime.h>

#define BB 8
#define TT 1024
#define DD 512
#define HH 8
#define HS 64

typedef __attribute__((ext_vector_type(8))) short short8;
typedef __attribute__((ext_vector_type(4))) float f32x4;
typedef __attribute__((ext_vector_type(16))) float f32x16;

__device__ __forceinline__ float bf2f(unsigned short u) {
  union { unsigned int i; float f; } v; v.i = ((unsigned int)u) << 16; return v.f;
}
__device__ __forceinline__ unsigned short f2bf(float f) {
  union { float f; unsigned int i; } v; v.f = f;
  unsigned int i = v.i;
  return (unsigned short)((i + 0x7FFFu + ((i >> 16) & 1u)) >> 16);
}
__device__ __forceinline__ unsigned int cvt_pk_bf16(float lo, float hi) {
  unsigned int r;
  asm volatile("v_cvt_pk_bf16_f32 %0, %1, %2" : "=v"(r) : "v"(lo), "v"(hi));
  return r;
}

// ---------------- LayerNorm: one block per row, bf16 output ----------------
__global__ __launch_bounds__(256) void ln_kernel(const float* __restrict__ in,
                                                 const float* __restrict__ gamma,
                                                 const float* __restrict__ beta,
                                                 unsigned short* __restrict__ x) {
  int row = blockIdx.x;
  const float* r = in + (size_t)row * DD;
  int t = threadIdx.x;
  float a = r[t];
  float b = r[t + 256];
  float s = a + b;
#pragma unroll
  for (int o = 32; o > 0; o >>= 1) s += __shfl_down(s, o);
  __shared__ float red[8];
  if ((t & 63) == 0) red[t >> 6] = s;
  __syncthreads();
  float mean = (red[0] + red[1] + red[2] + red[3]) * (1.0f / DD);
  float da = a - mean, db = b - mean;
  float vs = da * da + db * db;
#pragma unroll
  for (int o = 32; o > 0; o >>= 1) vs += __shfl_down(vs, o);
  __syncthreads();
  if ((t & 63) == 0) red[t >> 6] = vs;
  __syncthreads();
  float var = (red[0] + red[1] + red[2] + red[3]) * (1.0f / DD);
  float inv = rsqrtf(var + 1e-3f);
  unsigned short* xr = x + (size_t)row * DD;
  xr[t]       = f2bf(da * inv * gamma[t] + beta[t]);
  xr[t + 256] = f2bf(db * inv * gamma[t + 256] + beta[t + 256]);
}

// ---------------- weight transposes: [H][512][64] f32 -> [H][64][512] bf16 ----------------
__global__ __launch_bounds__(256) void transpose_qkvp(const float* __restrict__ Wq, const float* __restrict__ Wk,
                                                      const float* __restrict__ Wv, const float* __restrict__ Wp,
                                                      unsigned short* __restrict__ Tq, unsigned short* __restrict__ Tk,
                                                      unsigned short* __restrict__ Tv, unsigned short* __restrict__ Tp) {
  int h = blockIdx.x, sel = blockIdx.y;
  const float* in = sel == 0 ? Wq : sel == 1 ? Wk : sel == 2 ? Wv : Wp;
  unsigned short* out = sel == 0 ? Tq : sel == 1 ? Tk : sel == 2 ? Tv : Tp;
  __shared__ float Tl[64][65];
  int tid = threadIdx.x;
  int r = tid >> 2, qq = tid & 3;
  for (int t = 0; t < 8; ++t) {
    __syncthreads();
#pragma unroll
    for (int j = 0; j < 4; ++j)
      *(float4*)&Tl[r][qq * 16 + j * 4] =
          *(const float4*)(in + ((size_t)h * 512 + t * 64 + r) * 64 + qq * 16 + j * 4);
    __syncthreads();
#pragma unroll
    for (int j = 0; j < 4; ++j) {
      ushort4 u;
      u.x = f2bf(Tl[qq * 16 + j * 4 + 0][r]);
      u.y = f2bf(Tl[qq * 16 + j * 4 + 1][r]);
      u.z = f2bf(Tl[qq * 16 + j * 4 + 2][r]);
      u.w = f2bf(Tl[qq * 16 + j * 4 + 3][r]);
      *(ushort4*)(out + ((size_t)h * 64 + r) * 512 + t * 64 + qq * 16 + j * 4) = u;
    }
  }
}

// Wo: [512(k=h*64+o)][512(i)] f32 -> WoT [512(i)][512(k)] bf16
__global__ __launch_bounds__(256) void transpose_wo(const float* __restrict__ in,
                                                    unsigned short* __restrict__ out) {
  int tr = blockIdx.x, tc = blockIdx.y;
  __shared__ float Tl[64][65];
  int tid = threadIdx.x;
  int r = tid >> 2, qq = tid & 3;
#pragma unroll
  for (int j = 0; j < 4; ++j)
    *(float4*)&Tl[r][qq * 16 + j * 4] =
        *(const float4*)(in + ((size_t)tr * 64 + r) * 512 + tc * 64 + qq * 16 + j * 4);
  __syncthreads();
#pragma unroll
  for (int j = 0; j < 4; ++j) {
    ushort4 u;
    u.x = f2bf(Tl[qq * 16 + j * 4 + 0][r]);
    u.y = f2bf(Tl[qq * 16 + j * 4 + 1][r]);
    u.z = f2bf(Tl[qq * 16 + j * 4 + 2][r]);
    u.w = f2bf(Tl[qq * 16 + j * 4 + 3][r]);
    *(ushort4*)(out + ((size_t)tc * 64 + r) * 512 + tr * 64 + qq * 16 + j * 4) = u;
  }
}

// ---------------- MFMA projection kernels: 64x64 tile, K=512, 4 waves ----------------
#define PMF_PROLOG                                 \
  int tid = threadIdx.x;                           \
  int w = tid >> 6, l = tid & 63;                  \
  int l15 = l & 15, l4 = l >> 4;                   \
  int rb = blockIdx.x, h = blockIdx.y;             \
  int arow = rb * 64 + w * 16 + l15;               \
  f32x4 cf0 = {0.f,0.f,0.f,0.f}, cf1 = cf0, cf2 = cf0, cf3 = cf0;

#define PMF_KSTEP(AEXPR)                                                              \
  for (int k0 = 0; k0 < DD; k0 += 32) {                                               \
    short8 a = (AEXPR);                                                               \
    short8 b0 = *(const short8*)(Wth + (size_t)(0 * 16 + l15) * DD + k0 + l4 * 8);    \
    short8 b1 = *(const short8*)(Wth + (size_t)(1 * 16 + l15) * DD + k0 + l4 * 8);    \
    short8 b2 = *(const short8*)(Wth + (size_t)(2 * 16 + l15) * DD + k0 + l4 * 8);    \
    short8 b3 = *(const short8*)(Wth + (size_t)(3 * 16 + l15) * DD + k0 + l4 * 8);    \
    cf0 = __builtin_amdgcn_mfma_f32_16x16x32_bf16(a, b0, cf0, 0, 0, 0);               \
    cf1 = __builtin_amdgcn_mfma_f32_16x16x32_bf16(a, b1, cf1, 0, 0, 0);               \
    cf2 = __builtin_amdgcn_mfma_f32_16x16x32_bf16(a, b2, cf2, 0, 0, 0);               \
    cf3 = __builtin_amdgcn_mfma_f32_16x16x32_bf16(a, b3, cf3, 0, 0, 0);               \
  }

__device__ __forceinline__ short8 ldbf8(const unsigned short* p) { return *(const short8*)p; }

// Q projection -> QU/QV bf16 [B][H][T][HS], bias+scale folded
__global__ __launch_bounds__(256) void proj_mfma_q(const unsigned short* __restrict__ X,
                                                   const unsigned short* __restrict__ Wt,
                                                   const float* __restrict__ bu,
                                                   const float* __restrict__ bv,
                                                   unsigned short* __restrict__ QU,
                                                   unsigned short* __restrict__ QV) {
  PMF_PROLOG
  const unsigned short* Wth = Wt + (size_t)h * HS * DD;
  PMF_KSTEP(ldbf8(X + (size_t)arow * DD + k0 + l4 * 8))
  const float S = 0.125f;
  f32x4 cfs[4] = {cf0, cf1, cf2, cf3};
#pragma unroll
  for (int of = 0; of < 4; ++of) {
    int o = of * 16 + l15;
    float bum = bu[h * HS + o], bvm = bv[h * HS + o];
#pragma unroll
    for (int j = 0; j < 4; ++j) {
      int r = rb * 64 + w * 16 + l4 * 4 + j;
      int b = r >> 10, n = r & 1023;
      size_t base = (((size_t)b * HH + h) * TT + n) * HS + o;
      QU[base] = f2bf((cfs[of][j] + bum) * S);
      QV[base] = f2bf((cfs[of][j] + bvm) * S);
    }
  }
}

// K projection (bf16 in) -> bf16 [B][H][T][HS]
__global__ __launch_bounds__(256) void proj_mfma_k(const unsigned short* __restrict__ X,
                                                   const unsigned short* __restrict__ Wt,
                                                   unsigned short* __restrict__ Out) {
  PMF_PROLOG
  const unsigned short* Wth = Wt + (size_t)h * HS * DD;
  PMF_KSTEP(ldbf8(X + (size_t)arow * DD + k0 + l4 * 8))
  f32x4 cfs[4] = {cf0, cf1, cf2, cf3};
#pragma unroll
  for (int of = 0; of < 4; ++of) {
    int o = of * 16 + l15;
#pragma unroll
    for (int j = 0; j < 4; ++j) {
      int r = rb * 64 + w * 16 + l4 * 4 + j;
      int b = r >> 10, n = r & 1023;
      Out[(((size_t)b * HH + h) * TT + n) * HS + o] = f2bf(cfs[of][j]);
    }
  }
}

// P projection (f32 pos in) -> bf16 [B][H][T][HS]
__global__ __launch_bounds__(256) void proj_mfma_p(const float* __restrict__ Xf,
                                                   const unsigned short* __restrict__ Wt,
                                                   unsigned short* __restrict__ Out) {
  PMF_PROLOG
  const unsigned short* Wth = Wt + (size_t)h * HS * DD;
  for (int k0 = 0; k0 < DD; k0 += 32) {
    const float* ap = Xf + (size_t)arow * DD + k0 + l4 * 8;
    float4 av0 = *(const float4*)ap, av1 = *(const float4*)(ap + 4);
    short8 a;
    a[0] = (short)f2bf(av0.x); a[1] = (short)f2bf(av0.y); a[2] = (short)f2bf(av0.z); a[3] = (short)f2bf(av0.w);
    a[4] = (short)f2bf(av1.x); a[5] = (short)f2bf(av1.y); a[6] = (short)f2bf(av1.z); a[7] = (short)f2bf(av1.w);
    short8 b0 = *(const short8*)(Wth + (size_t)(0 * 16 + l15) * DD + k0 + l4 * 8);
    short8 b1 = *(const short8*)(Wth + (size_t)(1 * 16 + l15) * DD + k0 + l4 * 8);
    short8 b2 = *(const short8*)(Wth + (size_t)(2 * 16 + l15) * DD + k0 + l4 * 8);
    short8 b3 = *(const short8*)(Wth + (size_t)(3 * 16 + l15) * DD + k0 + l4 * 8);
    cf0 = __builtin_amdgcn_mfma_f32_16x16x32_bf16(a, b0, cf0, 0, 0, 0);
    cf1 = __builtin_amdgcn_mfma_f32_16x16x32_bf16(a, b1, cf1, 0, 0, 0);
    cf2 = __builtin_amdgcn_mfma_f32_16x16x32_bf16(a, b2, cf2, 0, 0, 0);
    cf3 = __builtin_amdgcn_mfma_f32_16x16x32_bf16(a, b3, cf3, 0, 0, 0);
  }
  f32x4 cfs[4] = {cf0, cf1, cf2, cf3};
#pragma unroll
  for (int of = 0; of < 4; ++of) {
    int o = of * 16 + l15;
#pragma unroll
    for (int j = 0; j < 4; ++j) {
      int r = rb * 64 + w * 16 + l4 * 4 + j;
      int b = r >> 10, n = r & 1023;
      Out[(((size_t)b * HH + h) * TT + n) * HS + o] = f2bf(cfs[of][j]);
    }
  }
}

// V projection -> TRANSPOSED bf16 [B][H][HS][T]
__global__ __launch_bounds__(256) void proj_mfma_v(const unsigned short* __restrict__ X,
                                                   const unsigned short* __restrict__ Wt,
                                                   unsigned short* __restrict__ Vt) {
  PMF_PROLOG
  const unsigned short* Wth = Wt + (size_t)h * HS * DD;
  PMF_KSTEP(ldbf8(X + (size_t)arow * DD + k0 + l4 * 8))
  __shared__ float Tl[64][65];
  f32x4 cfs[4] = {cf0, cf1, cf2, cf3};
#pragma unroll
  for (int of = 0; of < 4; ++of)
#pragma unroll
    for (int j = 0; j < 4; ++j)
      Tl[w * 16 + l4 * 4 + j][of * 16 + l15] = cfs[of][j];
  __syncthreads();
  int o = tid >> 2, qq = tid & 3;
  int b = rb >> 4;
  int n0 = (rb & 15) * 64;
  size_t base = (((size_t)b * HH + h) * HS + o) * TT + n0 + qq * 16;
  short8 p0, p1;
#pragma unroll
  for (int i = 0; i < 8; ++i) p0[i] = (short)f2bf(Tl[qq * 16 + i][o]);
#pragma unroll
  for (int i = 0; i < 8; ++i) p1[i] = (short)f2bf(Tl[qq * 16 + 8 + i][o]);
  *(short8*)(Vt + base) = p0;
  *(short8*)(Vt + base + 8) = p1;
}

// ---------------- output projection (MFMA) + bias + residual ----------------
__global__ __launch_bounds__(256) void out_mfma(const unsigned short* __restrict__ A,
                                                const unsigned short* __restrict__ WoT,
                                                const float* __restrict__ resid,
                                                const float* __restrict__ bias,
                                                float* __restrict__ Out) {
  int tid = threadIdx.x;
  int w = tid >> 6, l = tid & 63;
  int l15 = l & 15, l4 = l >> 4;
  int rb = blockIdx.x, cb = blockIdx.y;
  int arow = rb * 64 + w * 16 + l15;
  f32x4 cf0 = {0.f,0.f,0.f,0.f}, cf1 = cf0, cf2 = cf0, cf3 = cf0;
  const unsigned short* Wth = WoT + (size_t)cb * 64 * DD;
  PMF_KSTEP(ldbf8(A + (size_t)arow * DD + k0 + l4 * 8))
  f32x4 cfs[4] = {cf0, cf1, cf2, cf3};
#pragma unroll
  for (int of = 0; of < 4; ++of) {
    int i = cb * 64 + of * 16 + l15;
    float bi = bias[i];
#pragma unroll
    for (int j = 0; j < 4; ++j) {
      int r = rb * 64 + w * 16 + l4 * 4 + j;
      Out[(size_t)r * DD + i] = cfs[of][j] + bi + resid[(size_t)r * DD + i];
    }
  }
}

// ------------- fused rel-attention: swapped-operand 32x32 MFMA, QBLK=32, 8-way KV split -------------
// QU,QV,K,P: bf16 [B][H][T][64]; Vt: bf16 [B][H][64][T]; pre: bf16 [B][T][H*64]
__global__ __launch_bounds__(512) void attn_mfma(const unsigned short* __restrict__ QU,
                                                 const unsigned short* __restrict__ QV,
                                                 const unsigned short* __restrict__ Kg,
                                                 const unsigned short* __restrict__ Vt,
                                                 const unsigned short* __restrict__ Pg,
                                                 unsigned short* __restrict__ pre) {
  // XCD-aware swizzle: all 32 nb-blocks of a (b,h) pair land on one XCD (idx%8 constant)
  int i = blockIdx.x;                  // 0..2047
  int slot = i >> 3;                   // 0..255
  int p = (i & 7) * 8 + (slot >> 5);   // pair 0..63
  int nb = slot & 31;
  int b = p >> 3, h = p & 7;
  int n0 = nb * 32;
  __shared__ __align__(16) unsigned short Wl[33][1056];  // unshifted BD rows n0..n0+32 (69.7 KB)
  int tid = threadIdx.x;
  int w = tid >> 6, l = tid & 63;
  int l15 = l & 15, l4 = l >> 4;       // 16x16 ids (prepass)
  int l31 = l & 31, hi = l >> 5;       // 32x32 ids (main)
  size_t bh = (size_t)b * HH + h;
  const unsigned short* QUb = QU + bh * (TT * HS);
  const unsigned short* QVb = QV + bh * (TT * HS);
  const unsigned short* Kb  = Kg + bh * (TT * HS);
  const unsigned short* Pb  = Pg + bh * (TT * HS);
  const unsigned short* Vb  = Vt + bh * (HS * TT);

  // ---- prepass rows 0..31: W[r][c] = QV[n0+r] . P[c] via 16x16 MFMA (verbatim r4) ----
  {
    int rg = w >> 2, ch = w & 3;
    const unsigned short* arow = QVb + (size_t)(n0 + 16 * rg + l15) * HS;
    short8 a0 = *(const short8*)(arow + l4 * 8);
    short8 a1 = *(const short8*)(arow + 32 + l4 * 8);
    for (int cg = 0; cg < 16; ++cg) {
      int c0 = ch * 256 + cg * 16;
      const unsigned short* brow = Pb + (size_t)(c0 + l15) * HS;
      short8 b0 = *(const short8*)(brow + l4 * 8);
      short8 b1 = *(const short8*)(brow + 32 + l4 * 8);
      f32x4 acc = {0.f, 0.f, 0.f, 0.f};
      acc = __builtin_amdgcn_mfma_f32_16x16x32_bf16(a0, b0, acc, 0, 0, 0);
      acc = __builtin_amdgcn_mfma_f32_16x16x32_bf16(a1, b1, acc, 0, 0, 0);
      int r = 16 * rg + l4 * 4;
      int c = c0 + l15;
#pragma unroll
      for (int j = 0; j < 4; ++j) Wl[r + j][c] = f2bf(acc[j]);
    }
  }
  // ---- row 32 via 16x16 MFMA (tile rows 32..47, only row 32 kept); wave w -> cols [w*128,+128) ----
  {
    int qr = n0 + 32 + l15; if (qr > TT - 1) qr = TT - 1;
    const unsigned short* arow = QVb + (size_t)qr * HS;
    short8 a0 = *(const short8*)(arow + l4 * 8);
    short8 a1 = *(const short8*)(arow + 32 + l4 * 8);
    for (int cg = 0; cg < 8; ++cg) {
      int c0 = w * 128 + cg * 16;
      const unsigned short* brow = Pb + (size_t)(c0 + l15) * HS;
      short8 b0 = *(const short8*)(brow + l4 * 8);
      short8 b1 = *(const short8*)(brow + 32 + l4 * 8);
      f32x4 acc = {0.f, 0.f, 0.f, 0.f};
      acc = __builtin_amdgcn_mfma_f32_16x16x32_bf16(a0, b0, acc, 0, 0, 0);
      acc = __builtin_amdgcn_mfma_f32_16x16x32_bf16(a1, b1, acc, 0, 0, 0);
      if (l4 == 0) Wl[32][c0 + l15] = f2bf(acc[0]);   // tile-row 0 == abs row 32
    }
  }
  __syncthreads();

  // ---- main: every wave owns the same 32 q-rows; m-chunks strided 8-way across waves ----
  int n = n0 + l31;                 // this lane's q-row (global)
  int c1 = 1023 - n, c2 = -(n + 2); // gather column bases
  short8 qb0 = *(const short8*)(QUb + (size_t)n * HS + 0  + hi * 8);
  short8 qb1 = *(const short8*)(QUb + (size_t)n * HS + 16 + hi * 8);
  short8 qb2 = *(const short8*)(QUb + (size_t)n * HS + 32 + hi * 8);
  short8 qb3 = *(const short8*)(QUb + (size_t)n * HS + 48 + hi * 8);
  f32x16 Oa0 = {}, Oa1 = {};
  float run_m = -1e30f, run_l = 0.f;

#pragma unroll 1
  for (int ci = 0; ci < 4; ++ci) {
    int m0 = (ci * 8 + w) * 32;
    // S^T[m][q] via 4 chained 32x32x16 MFMAs (A=K rows m0.., B=Q cols)
    f32x16 s = {};
    {
      const unsigned short* kr = Kb + (size_t)(m0 + l31) * HS + hi * 8;
      s = __builtin_amdgcn_mfma_f32_32x32x16_bf16(*(const short8*)(kr +  0), qb0, s, 0, 0, 0);
      s = __builtin_amdgcn_mfma_f32_32x32x16_bf16(*(const short8*)(kr + 16), qb1, s, 0, 0, 0);
      s = __builtin_amdgcn_mfma_f32_32x32x16_bf16(*(const short8*)(kr + 32), qb2, s, 0, 0, 0);
      s = __builtin_amdgcn_mfma_f32_32x32x16_bf16(*(const short8*)(kr + 48), qb3, s, 0, 0, 0);
    }
    // BD gather-add (rel-shift as index math); reg i -> m = m0 + (i&3) + 8*(i>>2) + 4*hi
    float sv[16];
#pragma unroll
    for (int i2 = 0; i2 < 16; ++i2) {
      int m = m0 + (i2 & 3) + 8 * (i2 >> 2) + 4 * hi;
      bool below = (m <= n);
      int row = below ? l31 : (l31 + 1);
      int cc = m + (below ? c1 : c2);
      cc = cc < 0 ? 0 : cc;
      float bd = bf2f(Wl[row][cc]);
      bd = (m == n + 1) ? 0.f : bd;
      sv[i2] = s[i2] + bd;
    }
    // online softmax: in-register row reduce + ONE cross-half shfl each
    float mx = sv[0];
#pragma unroll
    for (int i2 = 1; i2 < 16; ++i2) mx = fmaxf(mx, sv[i2]);
    mx = fmaxf(mx, __shfl_xor(mx, 32));
    float M2 = fmaxf(run_m, mx);
    float fac = __expf(run_m - M2);
    float sum = 0.f;
#pragma unroll
    for (int i2 = 0; i2 < 16; ++i2) { sv[i2] = __expf(sv[i2] - M2); sum += sv[i2]; }
    sum += __shfl_xor(sum, 32);
    run_l = run_l * fac + sum;
    run_m = M2;
#pragma unroll
    for (int i2 = 0; i2 < 16; ++i2) { Oa0[i2] *= fac; Oa1[i2] *= fac; }
    // pack P to bf16 pairs + cross-half exchange -> PV B-fragments (in-register, no LDS)
    unsigned int wpk[8], xw[8];
#pragma unroll
    for (int j2 = 0; j2 < 8; ++j2) wpk[j2] = cvt_pk_bf16(sv[2 * j2], sv[2 * j2 + 1]);
#pragma unroll
    for (int j2 = 0; j2 < 8; ++j2) xw[j2] = __shfl_xor(wpk[j2], 32);
    short8 bp0, bp1;
    {
      unsigned int* u = (unsigned int*)&bp0;
      u[0] = hi ? xw[2] : wpk[0]; u[1] = hi ? xw[3] : wpk[1];
      u[2] = hi ? wpk[2] : xw[0]; u[3] = hi ? wpk[3] : xw[1];
      unsigned int* v2 = (unsigned int*)&bp1;
      v2[0] = hi ? xw[6] : wpk[4]; v2[1] = hi ? xw[7] : wpk[5];
      v2[2] = hi ? wpk[6] : xw[4]; v2[3] = hi ? wpk[7] : xw[5];
    }
    // PV: O^T[o][q] += V^T[o][m] P^T[m][q]
    {
      const unsigned short* vr0 = Vb + (size_t)l31 * TT + m0 + hi * 8;
      const unsigned short* vr1 = vr0 + (size_t)32 * TT;
      Oa0 = __builtin_amdgcn_mfma_f32_32x32x16_bf16(*(const short8*)(vr0),      bp0, Oa0, 0, 0, 0);
      Oa0 = __builtin_amdgcn_mfma_f32_32x32x16_bf16(*(const short8*)(vr0 + 16), bp1, Oa0, 0, 0, 0);
      Oa1 = __builtin_amdgcn_mfma_f32_32x32x16_bf16(*(const short8*)(vr1),      bp0, Oa1, 0, 0, 0);
      Oa1 = __builtin_amdgcn_mfma_f32_32x32x16_bf16(*(const short8*)(vr1 + 16), bp1, Oa1, 0, 0, 0);
    }
  }

  // ---- merge 8 partials through LDS (reuse Wl; per-wave region 2176 f32, stride-33 pad) ----
  __syncthreads();
  float* WLf = (float*)&Wl[0][0];
  float* myO = WLf + w * 2176;
#pragma unroll
  for (int i2 = 0; i2 < 16; ++i2) {
    int o0 = (i2 & 3) + 8 * (i2 >> 2) + 4 * hi;
    myO[o0 * 33 + l31]        = Oa0[i2];
    myO[(o0 + 32) * 33 + l31] = Oa1[i2];
  }
  if (l < 32) { myO[2112 + l * 2] = run_m; myO[2112 + l * 2 + 1] = run_l; }
  __syncthreads();
  // final: wave w -> q rows w*4..w*4+3; lane -> o = l (coalesced 128B stores)
#pragma unroll
  for (int q4 = 0; q4 < 4; ++q4) {
    int q = w * 4 + q4;
    float M = -1e30f;
#pragma unroll
    for (int w2 = 0; w2 < 8; ++w2) M = fmaxf(M, WLf[w2 * 2176 + 2112 + q * 2]);
    float denom = 0.f, val = 0.f;
#pragma unroll
    for (int w2 = 0; w2 < 8; ++w2) {
      float mw = WLf[w2 * 2176 + 2112 + q * 2];
      float lw = WLf[w2 * 2176 + 2112 + q * 2 + 1];
      float aw = __expf(mw - M);
      denom += lw * aw;
      val += WLf[w2 * 2176 + l * 33 + q] * aw;
    }
    pre[((size_t)b * TT + n0 + q) * DD + h * HS + l] = f2bf(val / denom);
  }
}

extern "C" void kernel_launch(void* const* d_in, const int* in_sizes, int n_in,
                              void* d_out, int out_size, void* d_ws, size_t ws_size,
                              hipStream_t stream) {
  const float* inputs = (const float*)d_in[0];
  const float* pos    = (const float*)d_in[1];
  const float* gamma  = (const float*)d_in[2];
  const float* beta   = (const float*)d_in[3];
  const float* Wq = (const float*)d_in[4];
  const float* Wk = (const float*)d_in[5];
  const float* Wv = (const float*)d_in[6];
  const float* Wp = (const float*)d_in[7];
  const float* bu = (const float*)d_in[8];
  const float* bv = (const float*)d_in[9];
  const float* Wo = (const float*)d_in[10];
  const float* bo = (const float*)d_in[11];
  float* out = (float*)d_out;
  unsigned short* w16 = (unsigned short*)d_ws;

  const size_t T2 = (size_t)BB * TT * DD;   // 4.19M elems per full tensor
  unsigned short* x_bf  = w16;              // 8 MB each
  unsigned short* pre_b = x_bf  + T2;
  unsigned short* QUp   = pre_b + T2;
  unsigned short* QVp   = QUp   + T2;
  unsigned short* Kp    = QVp   + T2;
  unsigned short* Vtp   = Kp    + T2;
  unsigned short* Pp    = Vtp   + T2;
  unsigned short* WtQ   = Pp    + T2;       // 512 KB each
  unsigned short* WtK   = WtQ + 262144;
  unsigned short* WtV   = WtK + 262144;
  unsigned short* WtP   = WtV + 262144;
  unsigned short* WoT   = WtP + 262144;

  transpose_qkvp<<<dim3(8, 4), dim3(256), 0, stream>>>(Wq, Wk, Wv, Wp, WtQ, WtK, WtV, WtP);
  transpose_wo<<<dim3(8, 8), dim3(256), 0, stream>>>(Wo, WoT);
  ln_kernel<<<dim3(BB * TT), dim3(256), 0, stream>>>(inputs, gamma, beta, x_bf);
  proj_mfma_q<<<dim3(128, 8), dim3(256), 0, stream>>>(x_bf, WtQ, bu, bv, QUp, QVp);
  proj_mfma_k<<<dim3(128, 8), dim3(256), 0, stream>>>(x_bf, WtK, Kp);
  proj_mfma_v<<<dim3(128, 8), dim3(256), 0, stream>>>(x_bf, WtV, Vtp);
  proj_mfma_p<<<dim3(128, 8), dim3(256), 0, stream>>>(pos, WtP, Pp);
  attn_mfma<<<dim3(2048), dim3(512), 0, stream>>>(QUp, QVp, Kp, Vtp, Pp, pre_b);
  out_mfma<<<dim3(128, 8), dim3(256), 0, stream>>>(pre_b, WoT, inputs, bo, out);
}

// Round 6
// 248.231 us; speedup vs baseline: 11.3654x; 1.5906x over previous
//
#include <hip/hip_runtime.h>

#define BB 8
#define TT 1024
#define DD 512
#define HH 8
#define HS 64

typedef __attribute__((ext_vector_type(8))) short short8;
typedef __attribute__((ext_vector_type(4))) float f32x4;
typedef __attribute__((ext_vector_type(16))) float f32x16;

__device__ __forceinline__ float bf2f(unsigned short u) {
  union { unsigned int i; float f; } v; v.i = ((unsigned int)u) << 16; return v.f;
}
__device__ __forceinline__ unsigned short f2bf(float f) {
  union { float f; unsigned int i; } v; v.f = f;
  unsigned int i = v.i;
  return (unsigned short)((i + 0x7FFFu + ((i >> 16) & 1u)) >> 16);
}
__device__ __forceinline__ unsigned int cvt_pk_bf16(float lo, float hi) {
  unsigned int r;
  asm volatile("v_cvt_pk_bf16_f32 %0, %1, %2" : "=v"(r) : "v"(lo), "v"(hi));
  return r;
}

// ===== Fragment-tiled layouts (all consumers load coalesced 1KB per wave) =====
// 32-row tiles (QK/PV 32x32 frags): T32[bh][n>>5][k>>4][(k>>3)&1][n&31][k&7]
__device__ __forceinline__ size_t t32_addr(int n, int k) {
  return (size_t)(n >> 5) * 2048 + ((k >> 4) * 512) + (((k >> 3) & 1) * 256) + ((n & 31) * 8) + (k & 7);
}
// 16-row tiles (prepass 16x16 frags): T16[bh][n>>4][k>>5][(k>>3)&3][n&15][k&7]
__device__ __forceinline__ size_t t16_addr(int n, int k) {
  return (size_t)(n >> 4) * 1024 + ((k >> 5) * 512) + (((k >> 3) & 3) * 128) + ((n & 15) * 8) + (k & 7);
}
// V tiles: VT[bh][m>>5][(m>>4)&1][o>>5][(m>>3)&1][o&31][m&7]
__device__ __forceinline__ size_t vt_addr(int o, int m) {
  return (size_t)(m >> 5) * 2048 + (((m >> 4) & 1) * 1024) + ((o >> 5) * 512) +
         (((m >> 3) & 1) * 256) + ((o & 31) * 8) + (m & 7);
}

// ---------------- LayerNorm: one block per row, bf16 output (row-major) ----------------
__global__ __launch_bounds__(256) void ln_kernel(const float* __restrict__ in,
                                                 const float* __restrict__ gamma,
                                                 const float* __restrict__ beta,
                                                 unsigned short* __restrict__ x) {
  int row = blockIdx.x;
  const float* r = in + (size_t)row * DD;
  int t = threadIdx.x;
  float a = r[t];
  float b = r[t + 256];
  float s = a + b;
#pragma unroll
  for (int o = 32; o > 0; o >>= 1) s += __shfl_down(s, o);
  __shared__ float red[8];
  if ((t & 63) == 0) red[t >> 6] = s;
  __syncthreads();
  float mean = (red[0] + red[1] + red[2] + red[3]) * (1.0f / DD);
  float da = a - mean, db = b - mean;
  float vs = da * da + db * db;
#pragma unroll
  for (int o = 32; o > 0; o >>= 1) vs += __shfl_down(vs, o);
  __syncthreads();
  if ((t & 63) == 0) red[t >> 6] = vs;
  __syncthreads();
  float var = (red[0] + red[1] + red[2] + red[3]) * (1.0f / DD);
  float inv = rsqrtf(var + 1e-3f);
  unsigned short* xr = x + (size_t)row * DD;
  xr[t]       = f2bf(da * inv * gamma[t] + beta[t]);
  xr[t + 256] = f2bf(db * inv * gamma[t + 256] + beta[t + 256]);
}

// ---- weight retile: W[h][512][64] f32 -> WT[h][of4][kk16][lane64][8] bf16 ----
__global__ __launch_bounds__(256) void retile_qkvp(const float* __restrict__ Wq, const float* __restrict__ Wk,
                                                   const float* __restrict__ Wv, const float* __restrict__ Wp,
                                                   unsigned short* __restrict__ Tq, unsigned short* __restrict__ Tk,
                                                   unsigned short* __restrict__ Tv, unsigned short* __restrict__ Tp) {
  int h = blockIdx.x, sel = blockIdx.y;
  const float* in = sel == 0 ? Wq : sel == 1 ? Wk : sel == 2 ? Wv : Wp;
  unsigned short* out = sel == 0 ? Tq : sel == 1 ? Tk : sel == 2 ? Tv : Tp;
  for (int idx = threadIdx.x; idx < 32768; idx += 256) {
    int of = idx >> 13, kk = (idx >> 9) & 15, l4 = (idx >> 7) & 3, l15 = (idx >> 3) & 15, e = idx & 7;
    int o = of * 16 + l15, k = kk * 32 + l4 * 8 + e;
    out[(size_t)h * 32768 + idx] = f2bf(in[(size_t)h * 32768 + k * 64 + o]);
  }
}

// ---- Wo retile: Wo[512(k)][512(i)] f32 -> WoTT[cb8][of4][kk16][lane][8] bf16 ----
__global__ __launch_bounds__(256) void retile_wo(const float* __restrict__ in,
                                                 unsigned short* __restrict__ out) {
  int cb = blockIdx.x;
  for (int idx = threadIdx.x; idx < 32768; idx += 256) {
    int of = idx >> 13, kk = (idx >> 9) & 15, l4 = (idx >> 7) & 3, l15 = (idx >> 3) & 15, e = idx & 7;
    int i = cb * 64 + of * 16 + l15, k = kk * 32 + l4 * 8 + e;
    out[(size_t)cb * 32768 + idx] = f2bf(in[(size_t)k * 512 + i]);
  }
}

// ---------------- MFMA projection kernels: 64x64 tile, K=512, 4 waves ----------------
#define PMF_PROLOG                                 \
  int tid = threadIdx.x;                           \
  int w = tid >> 6, l = tid & 63;                  \
  int l15 = l & 15, l4 = l >> 4;                   \
  int rb = blockIdx.x, h = blockIdx.y;             \
  int arow = rb * 64 + w * 16 + l15;               \
  f32x4 cf0 = {0.f,0.f,0.f,0.f}, cf1 = cf0, cf2 = cf0, cf3 = cf0;

// tiled-weight K-loop: B loads fully coalesced
#define PMF_KSTEP(AEXPR)                                                 \
  for (int k0 = 0; k0 < DD; k0 += 32) {                                  \
    short8 a = (AEXPR);                                                  \
    const unsigned short* wb = Wth + (k0 >> 5) * 512 + l * 8;            \
    short8 b0 = *(const short8*)(wb + 0 * 8192);                         \
    short8 b1 = *(const short8*)(wb + 1 * 8192);                         \
    short8 b2 = *(const short8*)(wb + 2 * 8192);                         \
    short8 b3 = *(const short8*)(wb + 3 * 8192);                         \
    cf0 = __builtin_amdgcn_mfma_f32_16x16x32_bf16(a, b0, cf0, 0, 0, 0);  \
    cf1 = __builtin_amdgcn_mfma_f32_16x16x32_bf16(a, b1, cf1, 0, 0, 0);  \
    cf2 = __builtin_amdgcn_mfma_f32_16x16x32_bf16(a, b2, cf2, 0, 0, 0);  \
    cf3 = __builtin_amdgcn_mfma_f32_16x16x32_bf16(a, b3, cf3, 0, 0, 0);  \
  }

__device__ __forceinline__ short8 ldbf8(const unsigned short* p) { return *(const short8*)p; }

// Q projection -> QU (32-tile), QV (16-tile); bias+scale folded
__global__ __launch_bounds__(256) void proj_mfma_q(const unsigned short* __restrict__ X,
                                                   const unsigned short* __restrict__ Wt,
                                                   const float* __restrict__ bu,
                                                   const float* __restrict__ bv,
                                                   unsigned short* __restrict__ QU,
                                                   unsigned short* __restrict__ QV) {
  PMF_PROLOG
  const unsigned short* Wth = Wt + (size_t)h * 32768;
  PMF_KSTEP(ldbf8(X + (size_t)arow * DD + k0 + l4 * 8))
  const float S = 0.125f;
  f32x4 cfs[4] = {cf0, cf1, cf2, cf3};
#pragma unroll
  for (int of = 0; of < 4; ++of) {
    int o = of * 16 + l15;
    float bum = bu[h * HS + o], bvm = bv[h * HS + o];
#pragma unroll
    for (int j = 0; j < 4; ++j) {
      int r = rb * 64 + w * 16 + l4 * 4 + j;
      int b = r >> 10, n = r & 1023;
      size_t bho = ((size_t)b * HH + h) * 65536;
      QU[bho + t32_addr(n, o)] = f2bf((cfs[of][j] + bum) * S);
      QV[bho + t16_addr(n, o)] = f2bf((cfs[of][j] + bvm) * S);
    }
  }
}

// K projection -> KT (32-tile)
__global__ __launch_bounds__(256) void proj_mfma_k(const unsigned short* __restrict__ X,
                                                   const unsigned short* __restrict__ Wt,
                                                   unsigned short* __restrict__ Out) {
  PMF_PROLOG
  const unsigned short* Wth = Wt + (size_t)h * 32768;
  PMF_KSTEP(ldbf8(X + (size_t)arow * DD + k0 + l4 * 8))
  f32x4 cfs[4] = {cf0, cf1, cf2, cf3};
#pragma unroll
  for (int of = 0; of < 4; ++of) {
    int o = of * 16 + l15;
#pragma unroll
    for (int j = 0; j < 4; ++j) {
      int r = rb * 64 + w * 16 + l4 * 4 + j;
      int b = r >> 10, n = r & 1023;
      Out[((size_t)b * HH + h) * 65536 + t32_addr(n, o)] = f2bf(cfs[of][j]);
    }
  }
}

// P projection (f32 pos in) -> PT (16-tile)
__global__ __launch_bounds__(256) void proj_mfma_p(const float* __restrict__ Xf,
                                                   const unsigned short* __restrict__ Wt,
                                                   unsigned short* __restrict__ Out) {
  PMF_PROLOG
  const unsigned short* Wth = Wt + (size_t)h * 32768;
  for (int k0 = 0; k0 < DD; k0 += 32) {
    const float* ap = Xf + (size_t)arow * DD + k0 + l4 * 8;
    float4 av0 = *(const float4*)ap, av1 = *(const float4*)(ap + 4);
    short8 a;
    a[0] = (short)f2bf(av0.x); a[1] = (short)f2bf(av0.y); a[2] = (short)f2bf(av0.z); a[3] = (short)f2bf(av0.w);
    a[4] = (short)f2bf(av1.x); a[5] = (short)f2bf(av1.y); a[6] = (short)f2bf(av1.z); a[7] = (short)f2bf(av1.w);
    const unsigned short* wb = Wth + (k0 >> 5) * 512 + l * 8;
    short8 b0 = *(const short8*)(wb + 0 * 8192);
    short8 b1 = *(const short8*)(wb + 1 * 8192);
    short8 b2 = *(const short8*)(wb + 2 * 8192);
    short8 b3 = *(const short8*)(wb + 3 * 8192);
    cf0 = __builtin_amdgcn_mfma_f32_16x16x32_bf16(a, b0, cf0, 0, 0, 0);
    cf1 = __builtin_amdgcn_mfma_f32_16x16x32_bf16(a, b1, cf1, 0, 0, 0);
    cf2 = __builtin_amdgcn_mfma_f32_16x16x32_bf16(a, b2, cf2, 0, 0, 0);
    cf3 = __builtin_amdgcn_mfma_f32_16x16x32_bf16(a, b3, cf3, 0, 0, 0);
  }
  f32x4 cfs[4] = {cf0, cf1, cf2, cf3};
#pragma unroll
  for (int of = 0; of < 4; ++of) {
    int o = of * 16 + l15;
#pragma unroll
    for (int j = 0; j < 4; ++j) {
      int r = rb * 64 + w * 16 + l4 * 4 + j;
      int b = r >> 10, n = r & 1023;
      Out[((size_t)b * HH + h) * 65536 + t16_addr(n, o)] = f2bf(cfs[of][j]);
    }
  }
}

// V projection -> VT (PV-fragment tiles), direct scatter (no LDS transpose)
__global__ __launch_bounds__(256) void proj_mfma_v(const unsigned short* __restrict__ X,
                                                   const unsigned short* __restrict__ Wt,
                                                   unsigned short* __restrict__ Vt) {
  PMF_PROLOG
  const unsigned short* Wth = Wt + (size_t)h * 32768;
  PMF_KSTEP(ldbf8(X + (size_t)arow * DD + k0 + l4 * 8))
  f32x4 cfs[4] = {cf0, cf1, cf2, cf3};
#pragma unroll
  for (int of = 0; of < 4; ++of) {
    int o = of * 16 + l15;
#pragma unroll
    for (int j = 0; j < 4; ++j) {
      int r = rb * 64 + w * 16 + l4 * 4 + j;
      int b = r >> 10, m = r & 1023;
      Vt[((size_t)b * HH + h) * 65536 + vt_addr(o, m)] = f2bf(cfs[of][j]);
    }
  }
}

// ---------------- output projection (MFMA, tiled weights) + bias + residual ----------------
__global__ __launch_bounds__(256) void out_mfma(const unsigned short* __restrict__ A,
                                                const unsigned short* __restrict__ WoTT,
                                                const float* __restrict__ resid,
                                                const float* __restrict__ bias,
                                                float* __restrict__ Out) {
  int tid = threadIdx.x;
  int w = tid >> 6, l = tid & 63;
  int l15 = l & 15, l4 = l >> 4;
  int rb = blockIdx.x, cb = blockIdx.y;
  int arow = rb * 64 + w * 16 + l15;
  f32x4 cf0 = {0.f,0.f,0.f,0.f}, cf1 = cf0, cf2 = cf0, cf3 = cf0;
  const unsigned short* Wth = WoTT + (size_t)cb * 32768;
  PMF_KSTEP(ldbf8(A + (size_t)arow * DD + k0 + l4 * 8))
  f32x4 cfs[4] = {cf0, cf1, cf2, cf3};
#pragma unroll
  for (int of = 0; of < 4; ++of) {
    int i = cb * 64 + of * 16 + l15;
    float bi = bias[i];
#pragma unroll
    for (int j = 0; j < 4; ++j) {
      int r = rb * 64 + w * 16 + l4 * 4 + j;
      Out[(size_t)r * DD + i] = cfs[of][j] + bi + resid[(size_t)r * DD + i];
    }
  }
}

// ------------- fused rel-attention: swapped-operand 32x32 MFMA, tiled operands -------------
// QT,KT: 32-tile; QVT,PT: 16-tile; VT: PV tiles; pre: bf16 [B][T][H*64] row-major
#define WLS 1026  // Wl row stride in ushorts = 513 words (odd) -> gather bank = l31 (bijective)
__global__ __launch_bounds__(512) void attn_mfma(const unsigned short* __restrict__ QT,
                                                 const unsigned short* __restrict__ QVT,
                                                 const unsigned short* __restrict__ KT,
                                                 const unsigned short* __restrict__ VT,
                                                 const unsigned short* __restrict__ PT,
                                                 unsigned short* __restrict__ pre) {
  // XCD-aware swizzle: all 32 nb-blocks of a (b,h) pair land on one XCD (idx%8 constant)
  int i = blockIdx.x;                  // 0..2047
  int slot = i >> 3;                   // 0..255
  int p = (i & 7) * 8 + (slot >> 5);   // pair 0..63
  int nb = slot & 31;
  int b = p >> 3, h = p & 7;
  int n0 = nb * 32;
  __shared__ __align__(16) unsigned short Wl[34][WLS];  // 69.8 KB; rows n0..n0+32 + merge reuse
  int tid = threadIdx.x;
  int w = tid >> 6, l = tid & 63;
  int l15 = l & 15, l4 = l >> 4;       // 16x16 ids (prepass)
  int l31 = l & 31, hi = l >> 5;       // 32x32 ids (main)
  size_t bh = ((size_t)b * HH + h) * 65536;
  const unsigned short* QTb  = QT  + bh;
  const unsigned short* QVb  = QVT + bh;
  const unsigned short* KTb  = KT  + bh;
  const unsigned short* PTb  = PT  + bh;
  const unsigned short* VTb  = VT  + bh;

  // ---- prepass rows 0..31: W[r][c] = QV[n0+r] . P[c] via 16x16 MFMA (coalesced frag loads) ----
  {
    int rg = w >> 2, ch = w & 3;
    const unsigned short* abase = QVb + (size_t)(nb * 2 + rg) * 1024 + l * 8;
    short8 a0 = *(const short8*)(abase);
    short8 a1 = *(const short8*)(abase + 512);
    for (int cg = 0; cg < 16; ++cg) {
      int ct = ch * 16 + cg;
      const unsigned short* bbase = PTb + (size_t)ct * 1024 + l * 8;
      short8 b0 = *(const short8*)(bbase);
      short8 b1 = *(const short8*)(bbase + 512);
      f32x4 acc = {0.f, 0.f, 0.f, 0.f};
      acc = __builtin_amdgcn_mfma_f32_16x16x32_bf16(a0, b0, acc, 0, 0, 0);
      acc = __builtin_amdgcn_mfma_f32_16x16x32_bf16(a1, b1, acc, 0, 0, 0);
      int r = 16 * rg + l4 * 4;
      int c = ct * 16 + l15;
#pragma unroll
      for (int j = 0; j < 4; ++j) Wl[r + j][c] = f2bf(acc[j]);
    }
  }
  // ---- row 32 via 16x16 MFMA (tile rows n0+32..n0+47, only row 32 kept); wave w -> cols [w*128,+128) ----
  {
    int qr = n0 + 32 + l15; if (qr > TT - 1) qr = TT - 1;
    const unsigned short* abase = QVb + (size_t)(qr >> 4) * 1024 + l4 * 128 + (qr & 15) * 8;
    short8 a0 = *(const short8*)(abase);
    short8 a1 = *(const short8*)(abase + 512);
    for (int cg = 0; cg < 8; ++cg) {
      int ct = w * 8 + cg;
      const unsigned short* bbase = PTb + (size_t)ct * 1024 + l * 8;
      short8 b0 = *(const short8*)(bbase);
      short8 b1 = *(const short8*)(bbase + 512);
      f32x4 acc = {0.f, 0.f, 0.f, 0.f};
      acc = __builtin_amdgcn_mfma_f32_16x16x32_bf16(a0, b0, acc, 0, 0, 0);
      acc = __builtin_amdgcn_mfma_f32_16x16x32_bf16(a1, b1, acc, 0, 0, 0);
      if (l4 == 0) Wl[32][ct * 16 + l15] = f2bf(acc[0]);
    }
  }
  __syncthreads();

  // ---- main: every wave owns the same 32 q-rows; m-chunks strided 8-way across waves ----
  int n = n0 + l31;                 // this lane's q-row (global)
  int c1 = 1023 - n, c2 = -(n + 2); // gather column bases
  const unsigned short* qtb = QTb + (size_t)nb * 2048 + l * 8;
  short8 qb0 = *(const short8*)(qtb);
  short8 qb1 = *(const short8*)(qtb + 512);
  short8 qb2 = *(const short8*)(qtb + 1024);
  short8 qb3 = *(const short8*)(qtb + 1536);
  f32x16 Oa0 = {}, Oa1 = {};
  float run_m = -1e30f, run_l = 0.f;

#pragma unroll 1
  for (int ci = 0; ci < 4; ++ci) {
    int mt = ci * 8 + w;
    // S^T[m][q] via 4 chained 32x32x16 MFMAs (A=K tile, B=Q tile) — coalesced frag loads
    f32x16 s = {};
    {
      const unsigned short* ktb = KTb + (size_t)mt * 2048 + l * 8;
      s = __builtin_amdgcn_mfma_f32_32x32x16_bf16(*(const short8*)(ktb),        qb0, s, 0, 0, 0);
      s = __builtin_amdgcn_mfma_f32_32x32x16_bf16(*(const short8*)(ktb + 512),  qb1, s, 0, 0, 0);
      s = __builtin_amdgcn_mfma_f32_32x32x16_bf16(*(const short8*)(ktb + 1024), qb2, s, 0, 0, 0);
      s = __builtin_amdgcn_mfma_f32_32x32x16_bf16(*(const short8*)(ktb + 1536), qb3, s, 0, 0, 0);
    }
    int m0 = mt * 32;
    // BD gather-add (rel-shift as index math); reg i -> m = m0 + (i&3) + 8*(i>>2) + 4*hi
    float sv[16];
#pragma unroll
    for (int i2 = 0; i2 < 16; ++i2) {
      int m = m0 + (i2 & 3) + 8 * (i2 >> 2) + 4 * hi;
      bool below = (m <= n);
      int row = below ? l31 : (l31 + 1);
      int cc = m + (below ? c1 : c2);
      cc = cc < 0 ? 0 : cc;
      float bd = bf2f(Wl[row][cc]);
      bd = (m == n + 1) ? 0.f : bd;
      sv[i2] = s[i2] + bd;
    }
    // online softmax: in-register row reduce + ONE cross-half shfl each
    float mx = sv[0];
#pragma unroll
    for (int i2 = 1; i2 < 16; ++i2) mx = fmaxf(mx, sv[i2]);
    mx = fmaxf(mx, __shfl_xor(mx, 32));
    float M2 = fmaxf(run_m, mx);
    float fac = __expf(run_m - M2);
    float sum = 0.f;
#pragma unroll
    for (int i2 = 0; i2 < 16; ++i2) { sv[i2] = __expf(sv[i2] - M2); sum += sv[i2]; }
    sum += __shfl_xor(sum, 32);
    run_l = run_l * fac + sum;
    run_m = M2;
#pragma unroll
    for (int i2 = 0; i2 < 16; ++i2) { Oa0[i2] *= fac; Oa1[i2] *= fac; }
    // pack P to bf16 pairs + cross-half exchange -> PV B-fragments (in-register)
    unsigned int wpk[8], xw[8];
#pragma unroll
    for (int j2 = 0; j2 < 8; ++j2) wpk[j2] = cvt_pk_bf16(sv[2 * j2], sv[2 * j2 + 1]);
#pragma unroll
    for (int j2 = 0; j2 < 8; ++j2) xw[j2] = __shfl_xor(wpk[j2], 32);
    short8 bp0, bp1;
    {
      unsigned int* u = (unsigned int*)&bp0;
      u[0] = hi ? xw[2] : wpk[0]; u[1] = hi ? xw[3] : wpk[1];
      u[2] = hi ? wpk[2] : xw[0]; u[3] = hi ? wpk[3] : xw[1];
      unsigned int* v2 = (unsigned int*)&bp1;
      v2[0] = hi ? xw[6] : wpk[4]; v2[1] = hi ? xw[7] : wpk[5];
      v2[2] = hi ? wpk[6] : xw[4]; v2[3] = hi ? wpk[7] : xw[5];
    }
    // PV: O^T[o][q] += V^T[o][m] P^T[m][q] — coalesced V frag loads
    {
      const unsigned short* vtb = VTb + (size_t)mt * 2048 + l * 8;
      Oa0 = __builtin_amdgcn_mfma_f32_32x32x16_bf16(*(const short8*)(vtb),        bp0, Oa0, 0, 0, 0);
      Oa0 = __builtin_amdgcn_mfma_f32_32x32x16_bf16(*(const short8*)(vtb + 1024), bp1, Oa0, 0, 0, 0);
      Oa1 = __builtin_amdgcn_mfma_f32_32x32x16_bf16(*(const short8*)(vtb + 512),  bp0, Oa1, 0, 0, 0);
      Oa1 = __builtin_amdgcn_mfma_f32_32x32x16_bf16(*(const short8*)(vtb + 1536), bp1, Oa1, 0, 0, 0);
    }
  }

  // ---- merge 8 partials through LDS (reuse Wl; per-wave region 2176 f32, stride-33 pad) ----
  __syncthreads();
  float* WLf = (float*)&Wl[0][0];
  float* myO = WLf + w * 2176;
#pragma unroll
  for (int i2 = 0; i2 < 16; ++i2) {
    int o0 = (i2 & 3) + 8 * (i2 >> 2) + 4 * hi;
    myO[o0 * 33 + l31]        = Oa0[i2];
    myO[(o0 + 32) * 33 + l31] = Oa1[i2];
  }
  if (l < 32) { myO[2112 + l * 2] = run_m; myO[2112 + l * 2 + 1] = run_l; }
  __syncthreads();
  // final: wave w -> q rows w*4..w*4+3; lane -> o = l (coalesced 128B stores)
#pragma unroll
  for (int q4 = 0; q4 < 4; ++q4) {
    int q = w * 4 + q4;
    float M = -1e30f;
#pragma unroll
    for (int w2 = 0; w2 < 8; ++w2) M = fmaxf(M, WLf[w2 * 2176 + 2112 + q * 2]);
    float denom = 0.f, val = 0.f;
#pragma unroll
    for (int w2 = 0; w2 < 8; ++w2) {
      float mw = WLf[w2 * 2176 + 2112 + q * 2];
      float lw = WLf[w2 * 2176 + 2112 + q * 2 + 1];
      float aw = __expf(mw - M);
      denom += lw * aw;
      val += WLf[w2 * 2176 + l * 33 + q] * aw;
    }
    pre[((size_t)b * TT + n0 + q) * DD + h * HS + l] = f2bf(val / denom);
  }
}

extern "C" void kernel_launch(void* const* d_in, const int* in_sizes, int n_in,
                              void* d_out, int out_size, void* d_ws, size_t ws_size,
                              hipStream_t stream) {
  const float* inputs = (const float*)d_in[0];
  const float* pos    = (const float*)d_in[1];
  const float* gamma  = (const float*)d_in[2];
  const float* beta   = (const float*)d_in[3];
  const float* Wq = (const float*)d_in[4];
  const float* Wk = (const float*)d_in[5];
  const float* Wv = (const float*)d_in[6];
  const float* Wp = (const float*)d_in[7];
  const float* bu = (const float*)d_in[8];
  const float* bv = (const float*)d_in[9];
  const float* Wo = (const float*)d_in[10];
  const float* bo = (const float*)d_in[11];
  float* out = (float*)d_out;
  unsigned short* w16 = (unsigned short*)d_ws;

  const size_t T2 = (size_t)BB * TT * DD;   // 4.19M elems per full tensor
  unsigned short* x_bf  = w16;              // 8 MB each
  unsigned short* pre_b = x_bf  + T2;
  unsigned short* QUp   = pre_b + T2;
  unsigned short* QVp   = QUp   + T2;
  unsigned short* Kp    = QVp   + T2;
  unsigned short* Vtp   = Kp    + T2;
  unsigned short* Pp    = Vtp   + T2;
  unsigned short* WtQ   = Pp    + T2;       // 512 KB each
  unsigned short* WtK   = WtQ + 262144;
  unsigned short* WtV   = WtK + 262144;
  unsigned short* WtP   = WtV + 262144;
  unsigned short* WoTT  = WtP + 262144;

  retile_qkvp<<<dim3(8, 4), dim3(256), 0, stream>>>(Wq, Wk, Wv, Wp, WtQ, WtK, WtV, WtP);
  retile_wo<<<dim3(8), dim3(256), 0, stream>>>(Wo, WoTT);
  ln_kernel<<<dim3(BB * TT), dim3(256), 0, stream>>>(inputs, gamma, beta, x_bf);
  proj_mfma_q<<<dim3(128, 8), dim3(256), 0, stream>>>(x_bf, WtQ, bu, bv, QUp, QVp);
  proj_mfma_k<<<dim3(128, 8), dim3(256), 0, stream>>>(x_bf, WtK, Kp);
  proj_mfma_v<<<dim3(128, 8), dim3(256), 0, stream>>>(x_bf, WtV, Vtp);
  proj_mfma_p<<<dim3(128, 8), dim3(256), 0, stream>>>(pos, WtP, Pp);
  attn_mfma<<<dim3(2048), dim3(512), 0, stream>>>(QUp, QVp, Kp, Vtp, Pp, pre_b);
  out_mfma<<<dim3(128, 8), dim3(256), 0, stream>>>(pre_b, WoTT, inputs, bo, out);
}